// Round 1
// baseline (3153.633 us; speedup 1.0000x reference)
//
#include <hip/hip_runtime.h>

#define DEV static __device__ __forceinline__

typedef float f32x4 __attribute__((ext_vector_type(4)));
typedef short s16x8 __attribute__((ext_vector_type(8)));
typedef __bf16 bf16x8 __attribute__((ext_vector_type(8)));

DEV unsigned short f2bf(float f) {
  union { float f; unsigned u; } v; v.f = f;
  unsigned r = v.u + 0x7FFFu + ((v.u >> 16) & 1u);
  return (unsigned short)(r >> 16);
}
DEV float bf2f(unsigned short h) {
  union { unsigned u; float f; } v; v.u = ((unsigned)h) << 16;
  return v.f;
}
DEV void g2l16(const void* g, void* l) {
  __builtin_amdgcn_global_load_lds((const __attribute__((address_space(1))) void*)g,
                                   (__attribute__((address_space(3))) void*)l, 16, 0, 0);
}
DEV f32x4 mfma16(bf16x8 a, bf16x8 b, f32x4 c) {
  return __builtin_amdgcn_mfma_f32_16x16x32_bf16(a, b, c, 0, 0, 0);
}

// ---------------------------------------------------------------------------
// Precompute: Householder Q per layer.  Q = prod of reflections.
// ---------------------------------------------------------------------------
__global__ void k_house(const float* __restrict__ VS, float* __restrict__ Qg) {
  __shared__ float Qs[64 * 64];
  __shared__ float vsh[64];
  const int l = blockIdx.x, t = threadIdx.x;  // 64 threads, t = column j
  for (int i = 0; i < 64; i++) Qs[i * 64 + t] = (i == t) ? 1.f : 0.f;
  for (int rr = 0; rr < 32; rr++) {
    __syncthreads();
    vsh[t] = VS[(size_t)l * 2048 + rr * 64 + t];
    __syncthreads();
    float vn = 1e-8f, w = 0.f;
    for (int i = 0; i < 64; i++) { float vi = vsh[i]; vn += vi * vi; w += vi * Qs[i * 64 + t]; }
    float sw2 = (2.f / vn) * w;
    for (int i = 0; i < 64; i++) Qs[i * 64 + t] -= vsh[i] * sw2;
  }
  __syncthreads();
  for (int i = 0; i < 64; i++) Qg[(size_t)l * 4096 + i * 64 + t] = Qs[i * 64 + t];
}

// ---------------------------------------------------------------------------
// Precompute: RoPE cos/sin tables [64 tokens][64 dims]
// ---------------------------------------------------------------------------
__global__ void k_rope(float* __restrict__ C, float* __restrict__ Sn) {
  int idx = blockIdx.x * 256 + threadIdx.x;
  if (idx >= 4096) return;
  int s = idx >> 6, d = idx & 63;
  int dh = d & 31;
  float coord = (dh < 16) ? (float)(s >> 3) : (float)(s & 7);
  int fi = dh & 15;
  float invf = powf(10000.f, -(float)fi / 16.f);
  float ang = coord * invf;
  C[idx] = cosf(ang);
  Sn[idx] = sinf(ang);
}

// ---------------------------------------------------------------------------
// Precompute: fold per-head Q^T into Wq,Wk; convert w_qkv -> chunked [N][K] bf16
// chunk layout (K-dim matrix width K): elem(m,k) at ((m>>4)*(K>>3)+(k>>3))*128+(m&15)*8+(k&7)
// ---------------------------------------------------------------------------
__global__ __launch_bounds__(256) void k_fold_qkv(const float* __restrict__ W,
                                                  const float* __restrict__ Qg,
                                                  unsigned short* __restrict__ out) {
  __shared__ float qrows[16 * 64];
  __shared__ float tr[16 * 256];
  const int l = blockIdx.x / 48, ng = blockIdx.x % 48;
  const int n0 = ng * 16, t = threadIdx.x;
  const float* Wl = W + (size_t)l * 256 * 768;
  float res[16];
  if (n0 < 512) {
    int part = n0 >> 8, h = (n0 & 255) >> 6, j0 = n0 & 63;
    for (int i = t; i < 1024; i += 256) {
      int jj = i >> 6, dd = i & 63;
      qrows[i] = Qg[(size_t)l * 4096 + (j0 + jj) * 64 + dd];
    }
    __syncthreads();
    const float* wrow = Wl + (size_t)t * 768 + part * 256 + h * 64;
    float wreg[64];
    for (int d = 0; d < 64; d++) wreg[d] = wrow[d];
    for (int jj = 0; jj < 16; jj++) {
      float a = 0.f;
      for (int d = 0; d < 64; d++) a += wreg[d] * qrows[jj * 64 + d];
      res[jj] = a;
    }
  } else {
    for (int jj = 0; jj < 16; jj++) res[jj] = Wl[(size_t)t * 768 + n0 + jj];
    __syncthreads();
  }
  __syncthreads();
  for (int jj = 0; jj < 16; jj++) tr[jj * 256 + t] = res[jj];
  __syncthreads();
  size_t base = (size_t)l * 196608 + (size_t)(n0 >> 4) * 4096;
  int kb = t >> 3, jn0 = (t & 7) * 2;
  s16x8 w0, w1;
  for (int u = 0; u < 8; u++) w0[u] = (short)f2bf(tr[jn0 * 256 + kb * 8 + u]);
  for (int u = 0; u < 8; u++) w1[u] = (short)f2bf(tr[(jn0 + 1) * 256 + kb * 8 + u]);
  *(s16x8*)(out + base + (size_t)t * 16) = w0;
  *(s16x8*)(out + base + (size_t)t * 16 + 8) = w1;
}

// ---------------------------------------------------------------------------
// Precompute: W2 = [w_out | w_out@w_gate] -> chunked [512][256] bf16
// ---------------------------------------------------------------------------
__global__ __launch_bounds__(256) void k_fold_w2(const float* __restrict__ WO,
                                                 const float* __restrict__ WG,
                                                 unsigned short* __restrict__ out) {
  __shared__ float wgs[256 * 16];
  __shared__ float tr[16 * 256];
  const int l = blockIdx.x >> 5, ng = blockIdx.x & 31;
  const int n0 = ng * 16, t = threadIdx.x;
  const float* WOl = WO + (size_t)l * 65536;
  float res[16];
  if (n0 < 256) {
    for (int jj = 0; jj < 16; jj++) res[jj] = WOl[(size_t)t * 256 + n0 + jj];
  } else {
    int c0 = n0 - 256;
    const float* WGl = WG + (size_t)l * 65536;
    for (int i = t; i < 4096; i += 256) {
      int k = i >> 4, c = i & 15;
      wgs[i] = WGl[(size_t)k * 256 + c0 + c];
    }
    __syncthreads();
    float a[16];
    for (int c = 0; c < 16; c++) a[c] = 0.f;
    for (int k = 0; k < 256; k++) {
      float wo = WOl[(size_t)t * 256 + k];
      for (int c = 0; c < 16; c++) a[c] += wo * wgs[k * 16 + c];
    }
    for (int c = 0; c < 16; c++) res[c] = a[c];
  }
  __syncthreads();
  for (int jj = 0; jj < 16; jj++) tr[jj * 256 + t] = res[jj];
  __syncthreads();
  size_t base = (size_t)l * 131072 + (size_t)(n0 >> 4) * 4096;
  int kb = t >> 3, jn0 = (t & 7) * 2;
  s16x8 w0, w1;
  for (int u = 0; u < 8; u++) w0[u] = (short)f2bf(tr[jn0 * 256 + kb * 8 + u]);
  for (int u = 0; u < 8; u++) w1[u] = (short)f2bf(tr[(jn0 + 1) * 256 + kb * 8 + u]);
  *(s16x8*)(out + base + (size_t)t * 16) = w0;
  *(s16x8*)(out + base + (size_t)t * 16 + 8) = w1;
}

// ---------------------------------------------------------------------------
// Precompute: w_mlp_gate [256][2048] -> chunked [2048][256] bf16
// ---------------------------------------------------------------------------
__global__ __launch_bounds__(256) void k_conv_wmg(const float* __restrict__ W,
                                                  unsigned short* __restrict__ out) {
  __shared__ float tr[16 * 256];
  const int l = blockIdx.x >> 7, ng = blockIdx.x & 127;
  const int n0 = ng * 16, t = threadIdx.x;
  const float* src = W + (size_t)l * 256 * 2048 + (size_t)t * 2048 + n0;
  for (int j = 0; j < 16; j++) tr[j * 256 + t] = src[j];
  __syncthreads();
  size_t base = (size_t)l * 524288 + (size_t)ng * 4096;
  int kb = t >> 3, jn0 = (t & 7) * 2;
  s16x8 w0, w1;
  for (int u = 0; u < 8; u++) w0[u] = (short)f2bf(tr[jn0 * 256 + kb * 8 + u]);
  for (int u = 0; u < 8; u++) w1[u] = (short)f2bf(tr[(jn0 + 1) * 256 + kb * 8 + u]);
  *(s16x8*)(out + base + (size_t)t * 16) = w0;
  *(s16x8*)(out + base + (size_t)t * 16 + 8) = w1;
}

// ---------------------------------------------------------------------------
// Precompute: w_mlp_out [1024][256] -> chunked [256][1024] bf16
// ---------------------------------------------------------------------------
__global__ __launch_bounds__(256) void k_conv_wmo(const float* __restrict__ W,
                                                  unsigned short* __restrict__ out) {
  __shared__ float tr[16 * 256];
  const int l = blockIdx.x >> 4, ng = blockIdx.x & 15;
  const int n0 = ng * 16, t = threadIdx.x;
  const float* Wl = W + (size_t)l * 1024 * 256;
  size_t base = (size_t)l * 262144 + (size_t)ng * 16384;
  for (int c4 = 0; c4 < 4; c4++) {
    int k0 = c4 * 256;
    for (int j = 0; j < 16; j++) tr[j * 256 + t] = Wl[(size_t)(k0 + t) * 256 + n0 + j];
    __syncthreads();
    int kb = t >> 3, jn0 = (t & 7) * 2;
    s16x8 w0, w1;
    for (int u = 0; u < 8; u++) w0[u] = (short)f2bf(tr[jn0 * 256 + kb * 8 + u]);
    for (int u = 0; u < 8; u++) w1[u] = (short)f2bf(tr[(jn0 + 1) * 256 + kb * 8 + u]);
    *(s16x8*)(out + base + (size_t)(k0 >> 3) * 128 + (size_t)t * 16) = w0;
    *(s16x8*)(out + base + (size_t)(k0 >> 3) * 128 + (size_t)t * 16 + 8) = w1;
    __syncthreads();
  }
}

// ---------------------------------------------------------------------------
// Precompute: Whp = w_head @ w_patch_out [256][12], bhp = b_head@w_patch_out + b_patch_out
// ---------------------------------------------------------------------------
__global__ __launch_bounds__(256) void k_fold_head(const float* __restrict__ WH,
                                                   const float* __restrict__ BH,
                                                   const float* __restrict__ WPO,
                                                   const float* __restrict__ BPO,
                                                   float* __restrict__ WHP,
                                                   float* __restrict__ BHP) {
  __shared__ float wpos[256 * 12];
  const int t = threadIdx.x;
  for (int i = t; i < 3072; i += 256) wpos[i] = WPO[i];
  __syncthreads();
  float a[12];
  for (int c = 0; c < 12; c++) a[c] = 0.f;
  const float* whrow = WH + (size_t)t * 256;
  for (int k = 0; k < 256; k++) {
    float w = whrow[k];
    for (int c = 0; c < 12; c++) a[c] += w * wpos[k * 12 + c];
  }
  for (int c = 0; c < 12; c++) WHP[t * 12 + c] = a[c];
  if (t < 12) {
    float b = BPO[t];
    for (int k = 0; k < 256; k++) b += BH[k] * wpos[k * 12 + t];
    BHP[t] = b;
  }
}

// ---------------------------------------------------------------------------
// Embed: patchify + fourier features -> x [M,256] f32
// ---------------------------------------------------------------------------
__global__ __launch_bounds__(256) void k_embed(const float* __restrict__ ZT,
                                               const float* __restrict__ LOGSNR,
                                               const float* __restrict__ WPI,
                                               const float* __restrict__ BPI,
                                               float* __restrict__ X) {
  __shared__ float zb[768];
  __shared__ float sp[8];
  const int b = blockIdx.x, t = threadIdx.x;
  for (int i = t; i < 768; i += 256) zb[i] = ZT[(size_t)b * 768 + i];
  if (t < 8) {
    float freq = 0.15707963267948966f * (float)(1 << (t & 3));  // 2pi/40 * 2^k
    float a = LOGSNR[b] * freq;
    sp[t] = (t < 4) ? sinf(a) : cosf(a);
  }
  __syncthreads();
  float wc[20];
  for (int j = 0; j < 20; j++) wc[j] = WPI[j * 256 + t];
  float bk = BPI[t];
  for (int s = 0; s < 64; s++) {
    int gy = s >> 3, gx = s & 7;
    float acc = bk;
    for (int j = 0; j < 12; j++) {
      int cch = j >> 2, py = (j >> 1) & 1, px = j & 1;
      acc += zb[cch * 256 + (gy * 2 + py) * 16 + gx * 2 + px] * wc[j];
    }
    for (int j = 0; j < 8; j++) acc += sp[j] * wc[12 + j];
    X[((size_t)b * 64 + s) * 256 + t] = acc;
  }
}

// ---------------------------------------------------------------------------
// RMS norm: x f32 [M,256] -> xn chunked bf16.  One block = 16 rows.
// ---------------------------------------------------------------------------
__global__ __launch_bounds__(256) void k_rms(const float* __restrict__ X,
                                             unsigned short* __restrict__ XN) {
  const int m0 = blockIdx.x * 16, t = threadIdx.x;
  const int r = t >> 4, cj = t & 15;
  const float* row = X + (size_t)(m0 + r) * 256 + cj * 16;
  float4 a = *(const float4*)(row);
  float4 b = *(const float4*)(row + 4);
  float4 c = *(const float4*)(row + 8);
  float4 d = *(const float4*)(row + 12);
  float ss = a.x * a.x + a.y * a.y + a.z * a.z + a.w * a.w +
             b.x * b.x + b.y * b.y + b.z * b.z + b.w * b.w +
             c.x * c.x + c.y * c.y + c.z * c.z + c.w * c.w +
             d.x * d.x + d.y * d.y + d.z * d.z + d.w * d.w;
  for (int o = 1; o < 16; o <<= 1) ss += __shfl_xor(ss, o, 64);
  float rq = rsqrtf(ss * (1.f / 256.f) + 1.1920929e-07f);
  s16x8 v0, v1;
  v0[0] = (short)f2bf(a.x * rq); v0[1] = (short)f2bf(a.y * rq);
  v0[2] = (short)f2bf(a.z * rq); v0[3] = (short)f2bf(a.w * rq);
  v0[4] = (short)f2bf(b.x * rq); v0[5] = (short)f2bf(b.y * rq);
  v0[6] = (short)f2bf(b.z * rq); v0[7] = (short)f2bf(b.w * rq);
  v1[0] = (short)f2bf(c.x * rq); v1[1] = (short)f2bf(c.y * rq);
  v1[2] = (short)f2bf(c.z * rq); v1[3] = (short)f2bf(c.w * rq);
  v1[4] = (short)f2bf(d.x * rq); v1[5] = (short)f2bf(d.y * rq);
  v1[6] = (short)f2bf(d.z * rq); v1[7] = (short)f2bf(d.w * rq);
  size_t base = ((size_t)blockIdx.x * 32 + cj * 2) * 128 + r * 8;
  *(s16x8*)(XN + base) = v0;
  *(s16x8*)(XN + base + 128) = v1;
}

// ---------------------------------------------------------------------------
// GEMM single-B (128x128 tile, m97 structure).  MODE 0: store bf16 row-major
// (width NT*128).  MODE 1: X[r][c] += acc + bias[c].
// A and Bw are chunked-layout bf16.
// ---------------------------------------------------------------------------
template <int KD, int NT, int MODE>
__global__ __launch_bounds__(256) void k_gemm_single(const unsigned short* __restrict__ A,
                                                     const unsigned short* __restrict__ Bw,
                                                     unsigned short* __restrict__ Cout,
                                                     const float* __restrict__ bias,
                                                     float* __restrict__ X) {
  __shared__ unsigned short sm[16384];
  unsigned short* la = sm;
  unsigned short* lb = sm + 4096;
  const int t = threadIdx.x;
  const int lane = t & 63, wv = t >> 6;
  const int bm = blockIdx.x / NT, bn = blockIdx.x % NT;
  const int m0 = bm * 128, n0 = bn * 128;
  const int wm = wv >> 1, wn = wv & 1;
  constexpr int KB8 = KD >> 3;

  f32x4 acc[4][4];
  f32x4 zz = {0.f, 0.f, 0.f, 0.f};
  for (int i = 0; i < 4; i++)
    for (int j = 0; j < 4; j++) acc[i][j] = zz;

  for (int k0 = 0; k0 < KD; k0 += 32) {
    const int kb0 = k0 >> 3;
    for (int ii = 0; ii < 2; ii++) {
      size_t mg = (size_t)(m0 >> 4) + ii * 4 + wv;
      g2l16(A + (mg * KB8 + kb0) * 128 + lane * 8, la + (ii * 4 + wv) * 512 + lane * 8);
    }
    for (int ii = 0; ii < 2; ii++) {
      size_t ng = (size_t)(n0 >> 4) + ii * 4 + wv;
      g2l16(Bw + (ng * KB8 + kb0) * 128 + lane * 8, lb + (ii * 4 + wv) * 512 + lane * 8);
    }
    __syncthreads();
    bf16x8 af[4], bb[4];
    for (int i = 0; i < 4; i++) af[i] = *(const bf16x8*)(la + (wm * 4 + i) * 512 + lane * 8);
    for (int j = 0; j < 4; j++) bb[j] = *(const bf16x8*)(lb + (wn * 4 + j) * 512 + lane * 8);
    for (int i = 0; i < 4; i++)
      for (int j = 0; j < 4; j++) acc[i][j] = mfma16(af[i], bb[j], acc[i][j]);
    __syncthreads();
  }

  const int lr = lane & 15, lg = lane >> 4;
  if constexpr (MODE == 0) {
    unsigned short* lc = sm;
    for (int i = 0; i < 4; i++)
      for (int j = 0; j < 4; j++)
        for (int e = 0; e < 4; e++) {
          int r = wm * 64 + i * 16 + lg * 4 + e;
          int c = wn * 64 + j * 16 + lr;
          lc[r * 128 + c] = f2bf(acc[i][j][e]);
        }
    __syncthreads();
    for (int p = 0; p < 8; p++) {
      int r = p * 16 + (t >> 4);
      int c = (t & 15) * 8;
      *(s16x8*)(Cout + (size_t)(m0 + r) * (NT * 128) + n0 + c) = *(const s16x8*)(lc + r * 128 + c);
    }
  } else {
    for (int i = 0; i < 4; i++)
      for (int j = 0; j < 4; j++) {
        int c = n0 + wn * 64 + j * 16 + lr;
        float bv = bias[c];
        for (int e = 0; e < 4; e++) {
          int r = m0 + wm * 64 + i * 16 + lg * 4 + e;
          X[(size_t)r * 256 + c] += acc[i][j][e] + bv;
        }
      }
  }
}

// ---------------------------------------------------------------------------
// GEMM dual-B (128x64 tile per set).  MODE 0 (attn out+gate):
//   X += acc0 * sigmoid(acc1 + bias[c]).
// MODE 1 (mlp gate): h = (acc1+bias[1024+c]) * gelu(acc0+bias[c]) -> chunked bf16 Hout (K=1024 layout).
// ---------------------------------------------------------------------------
template <int KD, int MODE>
__global__ __launch_bounds__(256) void k_gemm_dual(const unsigned short* __restrict__ A,
                                                   const unsigned short* __restrict__ B0,
                                                   const unsigned short* __restrict__ B1,
                                                   const float* __restrict__ bias,
                                                   float* __restrict__ X,
                                                   unsigned short* __restrict__ Hout,
                                                   int NT) {
  __shared__ unsigned short sm[8192];
  unsigned short* la = sm;
  unsigned short* lb0 = sm + 4096;
  unsigned short* lb1 = sm + 6144;
  const int t = threadIdx.x, lane = t & 63, wv = t >> 6;
  const int bm = blockIdx.x / NT, bn = blockIdx.x % NT;
  const int m0 = bm * 128, n0 = bn * 64;
  constexpr int KB8 = KD >> 3;
  f32x4 acc0[2][4], acc1[2][4];
  f32x4 zz = {0.f, 0.f, 0.f, 0.f};
  for (int i = 0; i < 2; i++)
    for (int j = 0; j < 4; j++) { acc0[i][j] = zz; acc1[i][j] = zz; }

  for (int k0 = 0; k0 < KD; k0 += 32) {
    const int kb0 = k0 >> 3;
    for (int ii = 0; ii < 2; ii++) {
      size_t mg = (size_t)(m0 >> 4) + ii * 4 + wv;
      g2l16(A + (mg * KB8 + kb0) * 128 + lane * 8, la + (ii * 4 + wv) * 512 + lane * 8);
    }
    size_t ng = (size_t)(n0 >> 4) + wv;
    g2l16(B0 + (ng * KB8 + kb0) * 128 + lane * 8, lb0 + wv * 512 + lane * 8);
    g2l16(B1 + (ng * KB8 + kb0) * 128 + lane * 8, lb1 + wv * 512 + lane * 8);
    __syncthreads();
    bf16x8 af[2];
    for (int i = 0; i < 2; i++) af[i] = *(const bf16x8*)(la + (wv * 2 + i) * 512 + lane * 8);
    for (int j = 0; j < 4; j++) {
      bf16x8 b0 = *(const bf16x8*)(lb0 + j * 512 + lane * 8);
      bf16x8 b1 = *(const bf16x8*)(lb1 + j * 512 + lane * 8);
      for (int i = 0; i < 2; i++) {
        acc0[i][j] = mfma16(af[i], b0, acc0[i][j]);
        acc1[i][j] = mfma16(af[i], b1, acc1[i][j]);
      }
    }
    __syncthreads();
  }

  const int lr = lane & 15, lg = lane >> 4;
  if constexpr (MODE == 0) {
    for (int i = 0; i < 2; i++)
      for (int j = 0; j < 4; j++) {
        int c = n0 + j * 16 + lr;
        float bv = bias[c];
        for (int e = 0; e < 4; e++) {
          int r = m0 + wv * 32 + i * 16 + lg * 4 + e;
          float o = acc0[i][j][e];
          float g = acc1[i][j][e] + bv;
          X[(size_t)r * 256 + c] += o / (1.f + __expf(-g));
        }
      }
  } else {
    unsigned short* lc = sm;
    for (int i = 0; i < 2; i++)
      for (int j = 0; j < 4; j++) {
        int cl = j * 16 + lr;
        float bg_ = bias[n0 + cl];
        float bv_ = bias[1024 + n0 + cl];
        for (int e = 0; e < 4; e++) {
          int rl = wv * 32 + i * 16 + lg * 4 + e;
          float g = acc0[i][j][e] + bg_;
          float vv = acc1[i][j][e] + bv_;
          float ge = 0.5f * g * (1.f + erff(g * 0.70710678118654752f));
          lc[rl * 64 + cl] = f2bf(vv * ge);
        }
      }
    __syncthreads();
    for (int it = 0; it < 4; it++) {
      int idx = it * 2048 + t * 8;
      int mg_l = idx >> 10, rem = idx & 1023;
      int kb_l = rem >> 7, r = (rem >> 3) & 15;
      *(s16x8*)(Hout + ((size_t)((m0 >> 4) + mg_l) * 128 + (n0 >> 3) + kb_l) * 128 + r * 8) =
          *(const s16x8*)(lc + (mg_l * 16 + r) * 64 + kb_l * 8);
    }
  }
}

// ---------------------------------------------------------------------------
// Attention: one block per (b, h).  RoPE on load; scores via MFMA; masked
// softmax; P@V; writes AO in chunked layout (K=256 matrix).
// ---------------------------------------------------------------------------
__global__ __launch_bounds__(256) void k_attn(const unsigned short* __restrict__ QKV,
                                              const float* __restrict__ CT,
                                              const float* __restrict__ ST,
                                              unsigned short* __restrict__ AO,
                                              int use_local) {
  __shared__ unsigned short sm[16384];
  unsigned short* qs = sm;           // 4096 (reused for O staging)
  unsigned short* ks = sm + 4096;
  unsigned short* vt = sm + 8192;
  unsigned short* ps = sm + 12288;
  const int blk = blockIdx.x;
  const int b = blk >> 2, h = blk & 3;
  const int t = threadIdx.x, lane = t & 63, wv = t >> 6;
  const size_t rowbase = (size_t)b * 64 * 768;

  {
    int s = t >> 2, dq = (t & 3) * 8;
    const unsigned short* qrow = QKV + rowbase + (size_t)s * 768 + h * 64;
    s16x8 qlo = *(const s16x8*)(qrow + dq);
    s16x8 qhi = *(const s16x8*)(qrow + dq + 32);
    s16x8 klo = *(const s16x8*)(qrow + 256 + dq);
    s16x8 khi = *(const s16x8*)(qrow + 256 + dq + 32);
    s16x8 oql, oqh, okl, okh;
    for (int e = 0; e < 8; e++) {
      float cl = CT[s * 64 + dq + e], sl = ST[s * 64 + dq + e];
      float ch = CT[s * 64 + dq + 32 + e], sh = ST[s * 64 + dq + 32 + e];
      float ql = bf2f((unsigned short)qlo[e]), qh = bf2f((unsigned short)qhi[e]);
      oql[e] = (short)f2bf((ql * cl - qh * sl) * 0.125f);
      oqh[e] = (short)f2bf((qh * ch + ql * sh) * 0.125f);
      float kl = bf2f((unsigned short)klo[e]), kh = bf2f((unsigned short)khi[e]);
      okl[e] = (short)f2bf(kl * cl - kh * sl);
      okh[e] = (short)f2bf(kh * ch + kl * sh);
    }
    int off_lo = (((s >> 4) * 8 + (dq >> 3)) * 16 + (s & 15)) * 8;
    int off_hi = (((s >> 4) * 8 + (dq >> 3) + 4) * 16 + (s & 15)) * 8;
    *(s16x8*)(qs + off_lo) = oql;
    *(s16x8*)(qs + off_hi) = oqh;
    *(s16x8*)(ks + off_lo) = okl;
    *(s16x8*)(ks + off_hi) = okh;
    // V transposed into chunked layout [d][s]
    int d0 = (t & 3) * 16;
    s16x8 v0 = *(const s16x8*)(qrow + 512 + d0);
    s16x8 v1 = *(const s16x8*)(qrow + 512 + d0 + 8);
    for (int e = 0; e < 8; e++) {
      int d = d0 + e;
      vt[(((d >> 4) * 8 + (s >> 3)) * 16 + (d & 15)) * 8 + (s & 7)] = (unsigned short)v0[e];
      d = d0 + 8 + e;
      vt[(((d >> 4) * 8 + (s >> 3)) * 16 + (d & 15)) * 8 + (s & 7)] = (unsigned short)v1[e];
    }
  }
  __syncthreads();

  // scores: wave wv owns query rows wv*16..wv*16+15
  f32x4 sc[4];
  f32x4 zz = {0.f, 0.f, 0.f, 0.f};
  for (int j = 0; j < 4; j++) sc[j] = zz;
  for (int kk = 0; kk < 2; kk++) {
    bf16x8 aq = *(const bf16x8*)(qs + wv * 1024 + kk * 512 + lane * 8);
    for (int j = 0; j < 4; j++)
      sc[j] = mfma16(aq, *(const bf16x8*)(ks + j * 1024 + kk * 512 + lane * 8), sc[j]);
  }

  const int lr = lane & 15, lg = lane >> 4;
  for (int e = 0; e < 4; e++) {
    int sq = wv * 16 + lg * 4 + e;
    int yq = sq >> 3, xq = sq & 7;
    float mx = -1e30f;
    float vals[4];
    for (int j = 0; j < 4; j++) {
      int sk = j * 16 + lr;
      float v = sc[j][e];
      if (use_local) {
        int dy = yq - (sk >> 3), dx = xq - (sk & 7);
        if (dy * dy + dx * dx > 6) v = -1e30f;
      }
      vals[j] = v;
      mx = fmaxf(mx, v);
    }
    for (int o = 1; o < 16; o <<= 1) mx = fmaxf(mx, __shfl_xor(mx, o, 64));
    float sum = 0.f;
    for (int j = 0; j < 4; j++) {
      float p = __expf(vals[j] - mx);
      vals[j] = p;
      sum += p;
    }
    for (int o = 1; o < 16; o <<= 1) sum += __shfl_xor(sum, o, 64);
    float inv = 1.f / sum;
    for (int j = 0; j < 4; j++) {
      int sk = j * 16 + lr;
      ps[((wv * 8 + (sk >> 3)) * 16 + (sq & 15)) * 8 + (sk & 7)] = f2bf(vals[j] * inv);
    }
  }
  __syncthreads();

  f32x4 oa[4];
  for (int j = 0; j < 4; j++) oa[j] = zz;
  for (int kk = 0; kk < 2; kk++) {
    bf16x8 ap = *(const bf16x8*)(ps + wv * 1024 + kk * 512 + lane * 8);
    for (int j = 0; j < 4; j++)
      oa[j] = mfma16(ap, *(const bf16x8*)(vt + j * 1024 + kk * 512 + lane * 8), oa[j]);
  }
  unsigned short* os = qs + wv * 1024;  // per-wave 16x64 staging
  for (int j = 0; j < 4; j++)
    for (int e = 0; e < 4; e++) os[(lg * 4 + e) * 64 + j * 16 + lr] = f2bf(oa[j][e]);
  __syncthreads();
  const size_t obase = ((size_t)(b * 4 + wv) * 32 + h * 8) * 128;
  for (int c = 0; c < 2; c++) {
    int idx = c * 64 + lane;
    int kb = idx >> 4, r = idx & 15;
    *(s16x8*)(AO + obase + (size_t)kb * 128 + r * 8) = *(const s16x8*)(os + r * 64 + kb * 8);
  }
}

// ---------------------------------------------------------------------------
// Final head: rms(x)*norm_w @ Whp + bhp -> unpatchify.  One block per b.
// ---------------------------------------------------------------------------
__global__ __launch_bounds__(256) void k_head(const float* __restrict__ X,
                                              const float* __restrict__ NW,
                                              const float* __restrict__ WHP,
                                              const float* __restrict__ BHP,
                                              float* __restrict__ OUT) {
  __shared__ float wh[256 * 12];
  __shared__ float nw[256];
  __shared__ float bh[12];
  const int b = blockIdx.x, t = threadIdx.x;
  for (int i = t; i < 3072; i += 256) wh[i] = WHP[i];
  nw[t] = NW[t];
  if (t < 12) bh[t] = BHP[t];
  __syncthreads();
  const int r = t >> 2, qd = t & 3;
  const float* row = X + ((size_t)b * 64 + r) * 256 + qd * 64;
  float ss = 0.f;
  for (int i = 0; i < 64; i++) ss += row[i] * row[i];
  ss += __shfl_xor(ss, 1, 64);
  ss += __shfl_xor(ss, 2, 64);
  float rq = rsqrtf(ss * (1.f / 256.f) + 1.1920929e-07f);
  float accs[12];
  for (int c = 0; c < 12; c++) accs[c] = 0.f;
  for (int i = 0; i < 64; i++) {
    float xf = row[i] * rq * nw[qd * 64 + i];
    const float* wr = wh + (qd * 64 + i) * 12;
    for (int c = 0; c < 12; c++) accs[c] += xf * wr[c];
  }
  for (int c = 0; c < 12; c++) {
    accs[c] += __shfl_xor(accs[c], 1, 64);
    accs[c] += __shfl_xor(accs[c], 2, 64);
  }
  int gy = r >> 3, gx = r & 7;
  for (int u = 0; u < 3; u++) {
    int c = qd * 3 + u;
    float val = accs[c] + bh[c];
    int ch = c >> 2, py = (c >> 1) & 1, px = c & 1;
    OUT[(size_t)b * 768 + ch * 256 + (gy * 2 + py) * 16 + (gx * 2 + px)] = val;
  }
}

// ---------------------------------------------------------------------------
extern "C" void kernel_launch(void* const* d_in, const int* in_sizes, int n_in,
                              void* d_out, int out_size, void* d_ws, size_t ws_size,
                              hipStream_t stream) {
  (void)n_in; (void)out_size; (void)ws_size;
  const float* z_t    = (const float*)d_in[0];
  const float* logsnr = (const float*)d_in[1];
  const float* wpi    = (const float*)d_in[2];
  const float* bpi    = (const float*)d_in[3];
  const float* vs     = (const float*)d_in[4];
  const float* wqkv   = (const float*)d_in[5];
  const float* wout   = (const float*)d_in[6];
  const float* wgate  = (const float*)d_in[7];
  const float* bgate  = (const float*)d_in[8];
  const float* wmg    = (const float*)d_in[9];
  const float* bmg    = (const float*)d_in[10];
  const float* wmo    = (const float*)d_in[11];
  const float* bmo    = (const float*)d_in[12];
  const float* nfw    = (const float*)d_in[13];
  const float* whead  = (const float*)d_in[14];
  const float* bhead  = (const float*)d_in[15];
  const float* wpo    = (const float*)d_in[16];
  const float* bpo    = (const float*)d_in[17];
  float* OUT = (float*)d_out;

  const int Bn = in_sizes[0] / 768;  // 1024
  const int Mtot = Bn * 64;          // 65536

  char* w = (char*)d_ws;
  auto alloc = [&](size_t bytes) {
    char* p = w;
    w += (bytes + 255) & ~(size_t)255;
    return p;
  };
  float* Qg  = (float*)alloc((size_t)8 * 4096 * 4);
  float* Ct  = (float*)alloc(4096 * 4);
  float* St  = (float*)alloc(4096 * 4);
  float* WHP = (float*)alloc(3072 * 4);
  float* BHP = (float*)alloc(64);
  unsigned short* WqkvS = (unsigned short*)alloc((size_t)8 * 768 * 256 * 2);
  unsigned short* W2S   = (unsigned short*)alloc((size_t)8 * 512 * 256 * 2);
  unsigned short* WmgS  = (unsigned short*)alloc((size_t)8 * 2048 * 256 * 2);
  unsigned short* WmoS  = (unsigned short*)alloc((size_t)8 * 256 * 1024 * 2);
  float* X = (float*)alloc((size_t)Mtot * 256 * 4);
  unsigned short* XN  = (unsigned short*)alloc((size_t)Mtot * 256 * 2);
  unsigned short* BIG = (unsigned short*)alloc((size_t)Mtot * 1024 * 2);
  unsigned short* QKVb = BIG;
  unsigned short* AOb  = BIG + (size_t)Mtot * 768;
  unsigned short* Hb   = BIG;

  k_house<<<8, 64, 0, stream>>>(vs, Qg);
  k_rope<<<16, 256, 0, stream>>>(Ct, St);
  k_fold_qkv<<<8 * 48, 256, 0, stream>>>(wqkv, Qg, WqkvS);
  k_fold_w2<<<8 * 32, 256, 0, stream>>>(wout, wgate, W2S);
  k_conv_wmg<<<8 * 128, 256, 0, stream>>>(wmg, WmgS);
  k_conv_wmo<<<8 * 16, 256, 0, stream>>>(wmo, WmoS);
  k_fold_head<<<1, 256, 0, stream>>>(whead, bhead, wpo, bpo, WHP, BHP);
  k_embed<<<Bn, 256, 0, stream>>>(z_t, logsnr, wpi, bpi, X);

  for (int l = 0; l < 8; l++) {
    k_rms<<<Mtot / 16, 256, 0, stream>>>(X, XN);
    k_gemm_single<256, 6, 0><<<(Mtot / 128) * 6, 256, 0, stream>>>(
        XN, WqkvS + (size_t)l * 196608, QKVb, nullptr, nullptr);
    k_attn<<<Bn * 4, 256, 0, stream>>>(QKVb, Ct, St, AOb, ((l + 1) % 4) ? 1 : 0);
    k_gemm_dual<256, 0><<<(Mtot / 128) * 4, 256, 0, stream>>>(
        AOb, W2S + (size_t)l * 131072, W2S + (size_t)l * 131072 + 65536,
        bgate + l * 256, X, nullptr, 4);
    k_rms<<<Mtot / 16, 256, 0, stream>>>(X, XN);
    k_gemm_dual<256, 1><<<(Mtot / 128) * 16, 256, 0, stream>>>(
        XN, WmgS + (size_t)l * 524288, WmgS + (size_t)l * 524288 + 262144,
        bmg + l * 2048, nullptr, Hb, 16);
    k_gemm_single<1024, 2, 1><<<(Mtot / 128) * 2, 256, 0, stream>>>(
        Hb, WmoS + (size_t)l * 262144, nullptr, bmo + l * 256, X);
  }
  k_head<<<Bn, 256, 0, stream>>>(X, nfw, WHP, BHP, OUT);
}

// Round 4
// 2648.636 us; speedup vs baseline: 1.1907x; 1.1907x over previous
//
#include <hip/hip_runtime.h>

#define DEV static __device__ __forceinline__

typedef float f32x4 __attribute__((ext_vector_type(4)));
typedef short s16x8 __attribute__((ext_vector_type(8)));
typedef __bf16 bf16x8 __attribute__((ext_vector_type(8)));

DEV unsigned short f2bf(float f) {
  union { float f; unsigned u; } v; v.f = f;
  unsigned r = v.u + 0x7FFFu + ((v.u >> 16) & 1u);
  return (unsigned short)(r >> 16);
}
DEV float bf2f(unsigned short h) {
  union { unsigned u; float f; } v; v.u = ((unsigned)h) << 16;
  return v.f;
}
DEV void g2l16(const void* g, void* l) {
  __builtin_amdgcn_global_load_lds((const __attribute__((address_space(1))) void*)g,
                                   (__attribute__((address_space(3))) void*)l, 16, 0, 0);
}
DEV f32x4 mfma16(bf16x8 a, bf16x8 b, f32x4 c) {
  return __builtin_amdgcn_mfma_f32_16x16x32_bf16(a, b, c, 0, 0, 0);
}
// XCD-aware chunked swizzle; grid must be divisible by 8 (all our GEMM grids are).
DEV int xcd_swz(int bid, int nwg) {
  return (bid & 7) * (nwg >> 3) + (bid >> 3);
}

// ---------------------------------------------------------------------------
// Precompute: Householder Q per layer.  Register-resident: lane t holds
// column t of Q in 64 VGPRs; v broadcast via shfl; no LDS.
// ---------------------------------------------------------------------------
__global__ void k_house(const float* __restrict__ VS, float* __restrict__ Qg) {
  const int l = blockIdx.x, t = threadIdx.x;  // 64 threads, t = column j
  float Qc[64];
#pragma unroll
  for (int i = 0; i < 64; i++) Qc[i] = (i == t) ? 1.f : 0.f;
  for (int rr = 0; rr < 32; rr++) {
    float vt = VS[(size_t)l * 2048 + rr * 64 + t];
    float vn = vt * vt;
#pragma unroll
    for (int o = 1; o < 64; o <<= 1) vn += __shfl_xor(vn, o, 64);
    float vv[64];
#pragma unroll
    for (int i = 0; i < 64; i++) vv[i] = __shfl(vt, i, 64);
    float w0 = 0.f, w1 = 0.f, w2 = 0.f, w3 = 0.f;
#pragma unroll
    for (int i = 0; i < 64; i += 4) {
      w0 = fmaf(vv[i + 0], Qc[i + 0], w0);
      w1 = fmaf(vv[i + 1], Qc[i + 1], w1);
      w2 = fmaf(vv[i + 2], Qc[i + 2], w2);
      w3 = fmaf(vv[i + 3], Qc[i + 3], w3);
    }
    float c = (2.f / (vn + 1e-8f)) * ((w0 + w1) + (w2 + w3));
#pragma unroll
    for (int i = 0; i < 64; i++) Qc[i] = fmaf(-vv[i], c, Qc[i]);
  }
#pragma unroll
  for (int i = 0; i < 64; i++) Qg[(size_t)l * 4096 + i * 64 + t] = Qc[i];
}

// ---------------------------------------------------------------------------
// Precompute: RoPE cos/sin tables [64 tokens][64 dims]
// ---------------------------------------------------------------------------
__global__ void k_rope(float* __restrict__ C, float* __restrict__ Sn) {
  int idx = blockIdx.x * 256 + threadIdx.x;
  if (idx >= 4096) return;
  int s = idx >> 6, d = idx & 63;
  int dh = d & 31;
  float coord = (dh < 16) ? (float)(s >> 3) : (float)(s & 7);
  int fi = dh & 15;
  float invf = powf(10000.f, -(float)fi / 16.f);
  float ang = coord * invf;
  C[idx] = cosf(ang);
  Sn[idx] = sinf(ang);
}

// ---------------------------------------------------------------------------
// Precompute: fold per-head Q^T into Wq,Wk; convert w_qkv -> chunked [N][K] bf16
// chunk layout (K-dim matrix width K): elem(m,k) at ((m>>4)*(K>>3)+(k>>3))*128+(m&15)*8+(k&7)
// ---------------------------------------------------------------------------
__global__ __launch_bounds__(256) void k_fold_qkv(const float* __restrict__ W,
                                                  const float* __restrict__ Qg,
                                                  unsigned short* __restrict__ out) {
  __shared__ float qrows[16 * 64];
  __shared__ float tr[16 * 256];
  const int l = blockIdx.x / 48, ng = blockIdx.x % 48;
  const int n0 = ng * 16, t = threadIdx.x;
  const float* Wl = W + (size_t)l * 256 * 768;
  float res[16];
  if (n0 < 512) {
    int part = n0 >> 8, h = (n0 & 255) >> 6, j0 = n0 & 63;
    for (int i = t; i < 1024; i += 256) {
      int jj = i >> 6, dd = i & 63;
      qrows[i] = Qg[(size_t)l * 4096 + (j0 + jj) * 64 + dd];
    }
    __syncthreads();
    const float* wrow = Wl + (size_t)t * 768 + part * 256 + h * 64;
    float wreg[64];
    for (int d = 0; d < 64; d++) wreg[d] = wrow[d];
    for (int jj = 0; jj < 16; jj++) {
      float a = 0.f;
      for (int d = 0; d < 64; d++) a += wreg[d] * qrows[jj * 64 + d];
      res[jj] = a;
    }
  } else {
    for (int jj = 0; jj < 16; jj++) res[jj] = Wl[(size_t)t * 768 + n0 + jj];
    __syncthreads();
  }
  __syncthreads();
  for (int jj = 0; jj < 16; jj++) tr[jj * 256 + t] = res[jj];
  __syncthreads();
  size_t base = (size_t)l * 196608 + (size_t)(n0 >> 4) * 4096;
  int kb = t >> 3, jn0 = (t & 7) * 2;
  s16x8 w0, w1;
  for (int u = 0; u < 8; u++) w0[u] = (short)f2bf(tr[jn0 * 256 + kb * 8 + u]);
  for (int u = 0; u < 8; u++) w1[u] = (short)f2bf(tr[(jn0 + 1) * 256 + kb * 8 + u]);
  *(s16x8*)(out + base + (size_t)t * 16) = w0;
  *(s16x8*)(out + base + (size_t)t * 16 + 8) = w1;
}

// ---------------------------------------------------------------------------
// Precompute: W2 = [w_out | w_out@w_gate] -> chunked [512][256] bf16
// ---------------------------------------------------------------------------
__global__ __launch_bounds__(256) void k_fold_w2(const float* __restrict__ WO,
                                                 const float* __restrict__ WG,
                                                 unsigned short* __restrict__ out) {
  __shared__ float wgs[256 * 16];
  __shared__ float tr[16 * 256];
  const int l = blockIdx.x >> 5, ng = blockIdx.x & 31;
  const int n0 = ng * 16, t = threadIdx.x;
  const float* WOl = WO + (size_t)l * 65536;
  float res[16];
  if (n0 < 256) {
    for (int jj = 0; jj < 16; jj++) res[jj] = WOl[(size_t)t * 256 + n0 + jj];
  } else {
    int c0 = n0 - 256;
    const float* WGl = WG + (size_t)l * 65536;
    for (int i = t; i < 4096; i += 256) {
      int k = i >> 4, c = i & 15;
      wgs[i] = WGl[(size_t)k * 256 + c0 + c];
    }
    __syncthreads();
    float a[16];
    for (int c = 0; c < 16; c++) a[c] = 0.f;
    for (int k = 0; k < 256; k++) {
      float wo = WOl[(size_t)t * 256 + k];
      for (int c = 0; c < 16; c++) a[c] += wo * wgs[k * 16 + c];
    }
    for (int c = 0; c < 16; c++) res[c] = a[c];
  }
  __syncthreads();
  for (int jj = 0; jj < 16; jj++) tr[jj * 256 + t] = res[jj];
  __syncthreads();
  size_t base = (size_t)l * 131072 + (size_t)(n0 >> 4) * 4096;
  int kb = t >> 3, jn0 = (t & 7) * 2;
  s16x8 w0, w1;
  for (int u = 0; u < 8; u++) w0[u] = (short)f2bf(tr[jn0 * 256 + kb * 8 + u]);
  for (int u = 0; u < 8; u++) w1[u] = (short)f2bf(tr[(jn0 + 1) * 256 + kb * 8 + u]);
  *(s16x8*)(out + base + (size_t)t * 16) = w0;
  *(s16x8*)(out + base + (size_t)t * 16 + 8) = w1;
}

// ---------------------------------------------------------------------------
// Precompute: w_mlp_gate [256][2048] -> chunked [2048][256] bf16
// ---------------------------------------------------------------------------
__global__ __launch_bounds__(256) void k_conv_wmg(const float* __restrict__ W,
                                                  unsigned short* __restrict__ out) {
  __shared__ float tr[16 * 256];
  const int l = blockIdx.x >> 7, ng = blockIdx.x & 127;
  const int n0 = ng * 16, t = threadIdx.x;
  const float* src = W + (size_t)l * 256 * 2048 + (size_t)t * 2048 + n0;
  for (int j = 0; j < 16; j++) tr[j * 256 + t] = src[j];
  __syncthreads();
  size_t base = (size_t)l * 524288 + (size_t)ng * 4096;
  int kb = t >> 3, jn0 = (t & 7) * 2;
  s16x8 w0, w1;
  for (int u = 0; u < 8; u++) w0[u] = (short)f2bf(tr[jn0 * 256 + kb * 8 + u]);
  for (int u = 0; u < 8; u++) w1[u] = (short)f2bf(tr[(jn0 + 1) * 256 + kb * 8 + u]);
  *(s16x8*)(out + base + (size_t)t * 16) = w0;
  *(s16x8*)(out + base + (size_t)t * 16 + 8) = w1;
}

// ---------------------------------------------------------------------------
// Precompute: w_mlp_out [1024][256] -> chunked [256][1024] bf16
// ---------------------------------------------------------------------------
__global__ __launch_bounds__(256) void k_conv_wmo(const float* __restrict__ W,
                                                  unsigned short* __restrict__ out) {
  __shared__ float tr[16 * 256];
  const int l = blockIdx.x >> 4, ng = blockIdx.x & 15;
  const int n0 = ng * 16, t = threadIdx.x;
  const float* Wl = W + (size_t)l * 1024 * 256;
  size_t base = (size_t)l * 262144 + (size_t)ng * 16384;
  for (int c4 = 0; c4 < 4; c4++) {
    int k0 = c4 * 256;
    for (int j = 0; j < 16; j++) tr[j * 256 + t] = Wl[(size_t)(k0 + t) * 256 + n0 + j];
    __syncthreads();
    int kb = t >> 3, jn0 = (t & 7) * 2;
    s16x8 w0, w1;
    for (int u = 0; u < 8; u++) w0[u] = (short)f2bf(tr[jn0 * 256 + kb * 8 + u]);
    for (int u = 0; u < 8; u++) w1[u] = (short)f2bf(tr[(jn0 + 1) * 256 + kb * 8 + u]);
    *(s16x8*)(out + base + (size_t)(k0 >> 3) * 128 + (size_t)t * 16) = w0;
    *(s16x8*)(out + base + (size_t)(k0 >> 3) * 128 + (size_t)t * 16 + 8) = w1;
    __syncthreads();
  }
}

// ---------------------------------------------------------------------------
// Precompute: Whp = w_head @ w_patch_out [256][12], bhp = b_head@w_patch_out + b_patch_out
// ---------------------------------------------------------------------------
__global__ __launch_bounds__(256) void k_fold_head(const float* __restrict__ WH,
                                                   const float* __restrict__ BH,
                                                   const float* __restrict__ WPO,
                                                   const float* __restrict__ BPO,
                                                   float* __restrict__ WHP,
                                                   float* __restrict__ BHP) {
  __shared__ float wpos[256 * 12];
  const int t = threadIdx.x;
  for (int i = t; i < 3072; i += 256) wpos[i] = WPO[i];
  __syncthreads();
  float a[12];
  for (int c = 0; c < 12; c++) a[c] = 0.f;
  const float* whrow = WH + (size_t)t * 256;
  for (int k = 0; k < 256; k++) {
    float w = whrow[k];
    for (int c = 0; c < 12; c++) a[c] += w * wpos[k * 12 + c];
  }
  for (int c = 0; c < 12; c++) WHP[t * 12 + c] = a[c];
  if (t < 12) {
    float b = BPO[t];
    for (int k = 0; k < 256; k++) b += BH[k] * wpos[k * 12 + t];
    BHP[t] = b;
  }
}

// ---------------------------------------------------------------------------
// Embed: patchify + fourier features -> x [M,256] f32
// ---------------------------------------------------------------------------
__global__ __launch_bounds__(256) void k_embed(const float* __restrict__ ZT,
                                               const float* __restrict__ LOGSNR,
                                               const float* __restrict__ WPI,
                                               const float* __restrict__ BPI,
                                               float* __restrict__ X) {
  __shared__ float zb[768];
  __shared__ float sp[8];
  const int b = blockIdx.x, t = threadIdx.x;
  for (int i = t; i < 768; i += 256) zb[i] = ZT[(size_t)b * 768 + i];
  if (t < 8) {
    float freq = 0.15707963267948966f * (float)(1 << (t & 3));  // 2pi/40 * 2^k
    float a = LOGSNR[b] * freq;
    sp[t] = (t < 4) ? sinf(a) : cosf(a);
  }
  __syncthreads();
  float wc[20];
  for (int j = 0; j < 20; j++) wc[j] = WPI[j * 256 + t];
  float bk = BPI[t];
  for (int s = 0; s < 64; s++) {
    int gy = s >> 3, gx = s & 7;
    float acc = bk;
    for (int j = 0; j < 12; j++) {
      int cch = j >> 2, py = (j >> 1) & 1, px = j & 1;
      acc += zb[cch * 256 + (gy * 2 + py) * 16 + gx * 2 + px] * wc[j];
    }
    for (int j = 0; j < 8; j++) acc += sp[j] * wc[12 + j];
    X[((size_t)b * 64 + s) * 256 + t] = acc;
  }
}

// ---------------------------------------------------------------------------
// RMS norm: x f32 [M,256] -> xn chunked bf16.  One block = 16 rows.
// ---------------------------------------------------------------------------
__global__ __launch_bounds__(256) void k_rms(const float* __restrict__ X,
                                             unsigned short* __restrict__ XN) {
  const int m0 = blockIdx.x * 16, t = threadIdx.x;
  const int r = t >> 4, cj = t & 15;
  const float* row = X + (size_t)(m0 + r) * 256 + cj * 16;
  float4 a = *(const float4*)(row);
  float4 b = *(const float4*)(row + 4);
  float4 c = *(const float4*)(row + 8);
  float4 d = *(const float4*)(row + 12);
  float ss = a.x * a.x + a.y * a.y + a.z * a.z + a.w * a.w +
             b.x * b.x + b.y * b.y + b.z * b.z + b.w * b.w +
             c.x * c.x + c.y * c.y + c.z * c.z + c.w * c.w +
             d.x * d.x + d.y * d.y + d.z * d.z + d.w * d.w;
  for (int o = 1; o < 16; o <<= 1) ss += __shfl_xor(ss, o, 64);
  float rq = rsqrtf(ss * (1.f / 256.f) + 1.1920929e-07f);
  s16x8 v0, v1;
  v0[0] = (short)f2bf(a.x * rq); v0[1] = (short)f2bf(a.y * rq);
  v0[2] = (short)f2bf(a.z * rq); v0[3] = (short)f2bf(a.w * rq);
  v0[4] = (short)f2bf(b.x * rq); v0[5] = (short)f2bf(b.y * rq);
  v0[6] = (short)f2bf(b.z * rq); v0[7] = (short)f2bf(b.w * rq);
  v1[0] = (short)f2bf(c.x * rq); v1[1] = (short)f2bf(c.y * rq);
  v1[2] = (short)f2bf(c.z * rq); v1[3] = (short)f2bf(c.w * rq);
  v1[4] = (short)f2bf(d.x * rq); v1[5] = (short)f2bf(d.y * rq);
  v1[6] = (short)f2bf(d.z * rq); v1[7] = (short)f2bf(d.w * rq);
  size_t base = ((size_t)blockIdx.x * 32 + cj * 2) * 128 + r * 8;
  *(s16x8*)(XN + base) = v0;
  *(s16x8*)(XN + base + 128) = v1;
}

// ---------------------------------------------------------------------------
// GEMM single-B (128x128 tile, m97 structure).  MODE 0: store bf16 row-major
// (width NT*128).  MODE 1: X[r][c] += acc + bias[c].
// A and Bw are chunked-layout bf16.
// ---------------------------------------------------------------------------
template <int KD, int NT, int MODE>
__global__ __launch_bounds__(256) void k_gemm_single(const unsigned short* __restrict__ A,
                                                     const unsigned short* __restrict__ Bw,
                                                     unsigned short* __restrict__ Cout,
                                                     const float* __restrict__ bias,
                                                     float* __restrict__ X) {
  __shared__ unsigned short sm[16384];
  unsigned short* la = sm;
  unsigned short* lb = sm + 4096;
  const int t = threadIdx.x;
  const int lane = t & 63, wv = t >> 6;
  const int swz = xcd_swz(blockIdx.x, gridDim.x);
  const int bm = swz / NT, bn = swz % NT;
  const int m0 = bm * 128, n0 = bn * 128;
  const int wm = wv >> 1, wn = wv & 1;
  constexpr int KB8 = KD >> 3;

  f32x4 acc[4][4];
  f32x4 zz = {0.f, 0.f, 0.f, 0.f};
  for (int i = 0; i < 4; i++)
    for (int j = 0; j < 4; j++) acc[i][j] = zz;

  for (int k0 = 0; k0 < KD; k0 += 32) {
    const int kb0 = k0 >> 3;
    for (int ii = 0; ii < 2; ii++) {
      size_t mg = (size_t)(m0 >> 4) + ii * 4 + wv;
      g2l16(A + (mg * KB8 + kb0) * 128 + lane * 8, la + (ii * 4 + wv) * 512 + lane * 8);
    }
    for (int ii = 0; ii < 2; ii++) {
      size_t ng = (size_t)(n0 >> 4) + ii * 4 + wv;
      g2l16(Bw + (ng * KB8 + kb0) * 128 + lane * 8, lb + (ii * 4 + wv) * 512 + lane * 8);
    }
    __syncthreads();
    bf16x8 af[4], bb[4];
    for (int i = 0; i < 4; i++) af[i] = *(const bf16x8*)(la + (wm * 4 + i) * 512 + lane * 8);
    for (int j = 0; j < 4; j++) bb[j] = *(const bf16x8*)(lb + (wn * 4 + j) * 512 + lane * 8);
    for (int i = 0; i < 4; i++)
      for (int j = 0; j < 4; j++) acc[i][j] = mfma16(af[i], bb[j], acc[i][j]);
    __syncthreads();
  }

  const int lr = lane & 15, lg = lane >> 4;
  if constexpr (MODE == 0) {
    unsigned short* lc = sm;
    for (int i = 0; i < 4; i++)
      for (int j = 0; j < 4; j++)
        for (int e = 0; e < 4; e++) {
          int r = wm * 64 + i * 16 + lg * 4 + e;
          int c = wn * 64 + j * 16 + lr;
          lc[r * 128 + c] = f2bf(acc[i][j][e]);
        }
    __syncthreads();
    for (int p = 0; p < 8; p++) {
      int r = p * 16 + (t >> 4);
      int c = (t & 15) * 8;
      *(s16x8*)(Cout + (size_t)(m0 + r) * (NT * 128) + n0 + c) = *(const s16x8*)(lc + r * 128 + c);
    }
  } else {
    for (int i = 0; i < 4; i++)
      for (int j = 0; j < 4; j++) {
        int c = n0 + wn * 64 + j * 16 + lr;
        float bv = bias[c];
        for (int e = 0; e < 4; e++) {
          int r = m0 + wm * 64 + i * 16 + lg * 4 + e;
          X[(size_t)r * 256 + c] += acc[i][j][e] + bv;
        }
      }
  }
}

// ---------------------------------------------------------------------------
// GEMM dual-B (128x64 tile per set).  MODE 0 (attn out+gate):
//   X += acc0 * sigmoid(acc1 + bias[c]).
// MODE 1 (mlp gate): h = (acc1+bias[1024+c]) * gelu(acc0+bias[c]) -> chunked bf16 Hout (K=1024 layout).
// ---------------------------------------------------------------------------
template <int KD, int MODE>
__global__ __launch_bounds__(256) void k_gemm_dual(const unsigned short* __restrict__ A,
                                                   const unsigned short* __restrict__ B0,
                                                   const unsigned short* __restrict__ B1,
                                                   const float* __restrict__ bias,
                                                   float* __restrict__ X,
                                                   unsigned short* __restrict__ Hout,
                                                   int NT) {
  __shared__ unsigned short sm[8192];
  unsigned short* la = sm;
  unsigned short* lb0 = sm + 4096;
  unsigned short* lb1 = sm + 6144;
  const int t = threadIdx.x, lane = t & 63, wv = t >> 6;
  const int swz = xcd_swz(blockIdx.x, gridDim.x);
  const int bm = swz / NT, bn = swz % NT;
  const int m0 = bm * 128, n0 = bn * 64;
  constexpr int KB8 = KD >> 3;
  f32x4 acc0[2][4], acc1[2][4];
  f32x4 zz = {0.f, 0.f, 0.f, 0.f};
  for (int i = 0; i < 2; i++)
    for (int j = 0; j < 4; j++) { acc0[i][j] = zz; acc1[i][j] = zz; }

  for (int k0 = 0; k0 < KD; k0 += 32) {
    const int kb0 = k0 >> 3;
    for (int ii = 0; ii < 2; ii++) {
      size_t mg = (size_t)(m0 >> 4) + ii * 4 + wv;
      g2l16(A + (mg * KB8 + kb0) * 128 + lane * 8, la + (ii * 4 + wv) * 512 + lane * 8);
    }
    size_t ng = (size_t)(n0 >> 4) + wv;
    g2l16(B0 + (ng * KB8 + kb0) * 128 + lane * 8, lb0 + wv * 512 + lane * 8);
    g2l16(B1 + (ng * KB8 + kb0) * 128 + lane * 8, lb1 + wv * 512 + lane * 8);
    __syncthreads();
    bf16x8 af[2];
    for (int i = 0; i < 2; i++) af[i] = *(const bf16x8*)(la + (wv * 2 + i) * 512 + lane * 8);
    for (int j = 0; j < 4; j++) {
      bf16x8 b0 = *(const bf16x8*)(lb0 + j * 512 + lane * 8);
      bf16x8 b1 = *(const bf16x8*)(lb1 + j * 512 + lane * 8);
      for (int i = 0; i < 2; i++) {
        acc0[i][j] = mfma16(af[i], b0, acc0[i][j]);
        acc1[i][j] = mfma16(af[i], b1, acc1[i][j]);
      }
    }
    __syncthreads();
  }

  const int lr = lane & 15, lg = lane >> 4;
  if constexpr (MODE == 0) {
    for (int i = 0; i < 2; i++)
      for (int j = 0; j < 4; j++) {
        int c = n0 + j * 16 + lr;
        float bv = bias[c];
        for (int e = 0; e < 4; e++) {
          int r = m0 + wv * 32 + i * 16 + lg * 4 + e;
          float o = acc0[i][j][e];
          float g = acc1[i][j][e] + bv;
          X[(size_t)r * 256 + c] += o / (1.f + __expf(-g));
        }
      }
  } else {
    unsigned short* lc = sm;
    for (int i = 0; i < 2; i++)
      for (int j = 0; j < 4; j++) {
        int cl = j * 16 + lr;
        float bg_ = bias[n0 + cl];
        float bv_ = bias[1024 + n0 + cl];
        for (int e = 0; e < 4; e++) {
          int rl = wv * 32 + i * 16 + lg * 4 + e;
          float g = acc0[i][j][e] + bg_;
          float vv = acc1[i][j][e] + bv_;
          float ge = 0.5f * g * (1.f + erff(g * 0.70710678118654752f));
          lc[rl * 64 + cl] = f2bf(vv * ge);
        }
      }
    __syncthreads();
    for (int it = 0; it < 4; it++) {
      int idx = it * 2048 + t * 8;
      int mg_l = idx >> 10, rem = idx & 1023;
      int kb_l = rem >> 7, r = (rem >> 3) & 15;
      *(s16x8*)(Hout + ((size_t)((m0 >> 4) + mg_l) * 128 + (n0 >> 3) + kb_l) * 128 + r * 8) =
          *(const s16x8*)(lc + (mg_l * 16 + r) * 64 + kb_l * 8);
    }
  }
}

// ---------------------------------------------------------------------------
// Attention: one block per (b, h).  RoPE on load; scores via MFMA; masked
// softmax; P@V; writes AO in chunked layout (K=256 matrix).
// ---------------------------------------------------------------------------
__global__ __launch_bounds__(256) void k_attn(const unsigned short* __restrict__ QKV,
                                              const float* __restrict__ CT,
                                              const float* __restrict__ ST,
                                              unsigned short* __restrict__ AO,
                                              int use_local) {
  __shared__ unsigned short sm[16384];
  unsigned short* qs = sm;           // 4096 (reused for O staging)
  unsigned short* ks = sm + 4096;
  unsigned short* vt = sm + 8192;
  unsigned short* ps = sm + 12288;
  const int blk = blockIdx.x;
  const int b = blk >> 2, h = blk & 3;
  const int t = threadIdx.x, lane = t & 63, wv = t >> 6;
  const size_t rowbase = (size_t)b * 64 * 768;

  {
    int s = t >> 2, dq = (t & 3) * 8;
    const unsigned short* qrow = QKV + rowbase + (size_t)s * 768 + h * 64;
    s16x8 qlo = *(const s16x8*)(qrow + dq);
    s16x8 qhi = *(const s16x8*)(qrow + dq + 32);
    s16x8 klo = *(const s16x8*)(qrow + 256 + dq);
    s16x8 khi = *(const s16x8*)(qrow + 256 + dq + 32);
    s16x8 oql, oqh, okl, okh;
    for (int e = 0; e < 8; e++) {
      float cl = CT[s * 64 + dq + e], sl = ST[s * 64 + dq + e];
      float ch = CT[s * 64 + dq + 32 + e], sh = ST[s * 64 + dq + 32 + e];
      float ql = bf2f((unsigned short)qlo[e]), qh = bf2f((unsigned short)qhi[e]);
      oql[e] = (short)f2bf((ql * cl - qh * sl) * 0.125f);
      oqh[e] = (short)f2bf((qh * ch + ql * sh) * 0.125f);
      float kl = bf2f((unsigned short)klo[e]), kh = bf2f((unsigned short)khi[e]);
      okl[e] = (short)f2bf(kl * cl - kh * sl);
      okh[e] = (short)f2bf(kh * ch + kl * sh);
    }
    int off_lo = (((s >> 4) * 8 + (dq >> 3)) * 16 + (s & 15)) * 8;
    int off_hi = (((s >> 4) * 8 + (dq >> 3) + 4) * 16 + (s & 15)) * 8;
    *(s16x8*)(qs + off_lo) = oql;
    *(s16x8*)(qs + off_hi) = oqh;
    *(s16x8*)(ks + off_lo) = okl;
    *(s16x8*)(ks + off_hi) = okh;
    // V transposed into chunked layout [d][s]
    int d0 = (t & 3) * 16;
    s16x8 v0 = *(const s16x8*)(qrow + 512 + d0);
    s16x8 v1 = *(const s16x8*)(qrow + 512 + d0 + 8);
    for (int e = 0; e < 8; e++) {
      int d = d0 + e;
      vt[(((d >> 4) * 8 + (s >> 3)) * 16 + (d & 15)) * 8 + (s & 7)] = (unsigned short)v0[e];
      d = d0 + 8 + e;
      vt[(((d >> 4) * 8 + (s >> 3)) * 16 + (d & 15)) * 8 + (s & 7)] = (unsigned short)v1[e];
    }
  }
  __syncthreads();

  // scores: wave wv owns query rows wv*16..wv*16+15
  f32x4 sc[4];
  f32x4 zz = {0.f, 0.f, 0.f, 0.f};
  for (int j = 0; j < 4; j++) sc[j] = zz;
  for (int kk = 0; kk < 2; kk++) {
    bf16x8 aq = *(const bf16x8*)(qs + wv * 1024 + kk * 512 + lane * 8);
    for (int j = 0; j < 4; j++)
      sc[j] = mfma16(aq, *(const bf16x8*)(ks + j * 1024 + kk * 512 + lane * 8), sc[j]);
  }

  const int lr = lane & 15, lg = lane >> 4;
  for (int e = 0; e < 4; e++) {
    int sq = wv * 16 + lg * 4 + e;
    int yq = sq >> 3, xq = sq & 7;
    float mx = -1e30f;
    float vals[4];
    for (int j = 0; j < 4; j++) {
      int sk = j * 16 + lr;
      float v = sc[j][e];
      if (use_local) {
        int dy = yq - (sk >> 3), dx = xq - (sk & 7);
        if (dy * dy + dx * dx > 6) v = -1e30f;
      }
      vals[j] = v;
      mx = fmaxf(mx, v);
    }
    for (int o = 1; o < 16; o <<= 1) mx = fmaxf(mx, __shfl_xor(mx, o, 64));
    float sum = 0.f;
    for (int j = 0; j < 4; j++) {
      float p = __expf(vals[j] - mx);
      vals[j] = p;
      sum += p;
    }
    for (int o = 1; o < 16; o <<= 1) sum += __shfl_xor(sum, o, 64);
    float inv = 1.f / sum;
    for (int j = 0; j < 4; j++) {
      int sk = j * 16 + lr;
      ps[((wv * 8 + (sk >> 3)) * 16 + (sq & 15)) * 8 + (sk & 7)] = f2bf(vals[j] * inv);
    }
  }
  __syncthreads();

  f32x4 oa[4];
  for (int j = 0; j < 4; j++) oa[j] = zz;
  for (int kk = 0; kk < 2; kk++) {
    bf16x8 ap = *(const bf16x8*)(ps + wv * 1024 + kk * 512 + lane * 8);
    for (int j = 0; j < 4; j++)
      oa[j] = mfma16(ap, *(const bf16x8*)(vt + j * 1024 + kk * 512 + lane * 8), oa[j]);
  }
  unsigned short* os = qs + wv * 1024;  // per-wave 16x64 staging
  for (int j = 0; j < 4; j++)
    for (int e = 0; e < 4; e++) os[(lg * 4 + e) * 64 + j * 16 + lr] = f2bf(oa[j][e]);
  __syncthreads();
  const size_t obase = ((size_t)(b * 4 + wv) * 32 + h * 8) * 128;
  for (int c = 0; c < 2; c++) {
    int idx = c * 64 + lane;
    int kb = idx >> 4, r = idx & 15;
    *(s16x8*)(AO + obase + (size_t)kb * 128 + r * 8) = *(const s16x8*)(os + r * 64 + kb * 8);
  }
}

// ---------------------------------------------------------------------------
// Final head: rms(x)*norm_w @ Whp + bhp -> unpatchify.  One block per b.
// ---------------------------------------------------------------------------
__global__ __launch_bounds__(256) void k_head(const float* __restrict__ X,
                                              const float* __restrict__ NW,
                                              const float* __restrict__ WHP,
                                              const float* __restrict__ BHP,
                                              float* __restrict__ OUT) {
  __shared__ float wh[256 * 12];
  __shared__ float nw[256];
  __shared__ float bh[12];
  const int b = blockIdx.x, t = threadIdx.x;
  for (int i = t; i < 3072; i += 256) wh[i] = WHP[i];
  nw[t] = NW[t];
  if (t < 12) bh[t] = BHP[t];
  __syncthreads();
  const int r = t >> 2, qd = t & 3;
  const float* row = X + ((size_t)b * 64 + r) * 256 + qd * 64;
  float ss = 0.f;
  for (int i = 0; i < 64; i++) ss += row[i] * row[i];
  ss += __shfl_xor(ss, 1, 64);
  ss += __shfl_xor(ss, 2, 64);
  float rq = rsqrtf(ss * (1.f / 256.f) + 1.1920929e-07f);
  float accs[12];
  for (int c = 0; c < 12; c++) accs[c] = 0.f;
  for (int i = 0; i < 64; i++) {
    float xf = row[i] * rq * nw[qd * 64 + i];
    const float* wr = wh + (qd * 64 + i) * 12;
    for (int c = 0; c < 12; c++) accs[c] += xf * wr[c];
  }
  for (int c = 0; c < 12; c++) {
    accs[c] += __shfl_xor(accs[c], 1, 64);
    accs[c] += __shfl_xor(accs[c], 2, 64);
  }
  int gy = r >> 3, gx = r & 7;
  for (int u = 0; u < 3; u++) {
    int c = qd * 3 + u;
    float val = accs[c] + bh[c];
    int ch = c >> 2, py = (c >> 1) & 1, px = c & 1;
    OUT[(size_t)b * 768 + ch * 256 + (gy * 2 + py) * 16 + (gx * 2 + px)] = val;
  }
}

// ---------------------------------------------------------------------------
extern "C" void kernel_launch(void* const* d_in, const int* in_sizes, int n_in,
                              void* d_out, int out_size, void* d_ws, size_t ws_size,
                              hipStream_t stream) {
  (void)n_in; (void)out_size; (void)ws_size;
  const float* z_t    = (const float*)d_in[0];
  const float* logsnr = (const float*)d_in[1];
  const float* wpi    = (const float*)d_in[2];
  const float* bpi    = (const float*)d_in[3];
  const float* vs     = (const float*)d_in[4];
  const float* wqkv   = (const float*)d_in[5];
  const float* wout   = (const float*)d_in[6];
  const float* wgate  = (const float*)d_in[7];
  const float* bgate  = (const float*)d_in[8];
  const float* wmg    = (const float*)d_in[9];
  const float* bmg    = (const float*)d_in[10];
  const float* wmo    = (const float*)d_in[11];
  const float* bmo    = (const float*)d_in[12];
  const float* nfw    = (const float*)d_in[13];
  const float* whead  = (const float*)d_in[14];
  const float* bhead  = (const float*)d_in[15];
  const float* wpo    = (const float*)d_in[16];
  const float* bpo    = (const float*)d_in[17];
  float* OUT = (float*)d_out;

  const int Bn = in_sizes[0] / 768;  // 1024
  const int Mtot = Bn * 64;          // 65536

  char* w = (char*)d_ws;
  auto alloc = [&](size_t bytes) {
    char* p = w;
    w += (bytes + 255) & ~(size_t)255;
    return p;
  };
  float* Qg  = (float*)alloc((size_t)8 * 4096 * 4);
  float* Ct  = (float*)alloc(4096 * 4);
  float* St  = (float*)alloc(4096 * 4);
  float* WHP = (float*)alloc(3072 * 4);
  float* BHP = (float*)alloc(64);
  unsigned short* WqkvS = (unsigned short*)alloc((size_t)8 * 768 * 256 * 2);
  unsigned short* W2S   = (unsigned short*)alloc((size_t)8 * 512 * 256 * 2);
  unsigned short* WmgS  = (unsigned short*)alloc((size_t)8 * 2048 * 256 * 2);
  unsigned short* WmoS  = (unsigned short*)alloc((size_t)8 * 256 * 1024 * 2);
  float* X = (float*)alloc((size_t)Mtot * 256 * 4);
  unsigned short* XN  = (unsigned short*)alloc((size_t)Mtot * 256 * 2);
  unsigned short* BIG = (unsigned short*)alloc((size_t)Mtot * 1024 * 2);
  unsigned short* QKVb = BIG;
  unsigned short* AOb  = BIG + (size_t)Mtot * 768;
  unsigned short* Hb   = BIG;

  k_house<<<8, 64, 0, stream>>>(vs, Qg);
  k_rope<<<16, 256, 0, stream>>>(Ct, St);
  k_fold_qkv<<<8 * 48, 256, 0, stream>>>(wqkv, Qg, WqkvS);
  k_fold_w2<<<8 * 32, 256, 0, stream>>>(wout, wgate, W2S);
  k_conv_wmg<<<8 * 128, 256, 0, stream>>>(wmg, WmgS);
  k_conv_wmo<<<8 * 16, 256, 0, stream>>>(wmo, WmoS);
  k_fold_head<<<1, 256, 0, stream>>>(whead, bhead, wpo, bpo, WHP, BHP);
  k_embed<<<Bn, 256, 0, stream>>>(z_t, logsnr, wpi, bpi, X);

  for (int l = 0; l < 8; l++) {
    k_rms<<<Mtot / 16, 256, 0, stream>>>(X, XN);
    k_gemm_single<256, 6, 0><<<(Mtot / 128) * 6, 256, 0, stream>>>(
        XN, WqkvS + (size_t)l * 196608, QKVb, nullptr, nullptr);
    k_attn<<<Bn * 4, 256, 0, stream>>>(QKVb, Ct, St, AOb, ((l + 1) % 4) ? 1 : 0);
    k_gemm_dual<256, 0><<<(Mtot / 128) * 4, 256, 0, stream>>>(
        AOb, W2S + (size_t)l * 131072, W2S + (size_t)l * 131072 + 65536,
        bgate + l * 256, X, nullptr, 4);
    k_rms<<<Mtot / 16, 256, 0, stream>>>(X, XN);
    k_gemm_dual<256, 1><<<(Mtot / 128) * 16, 256, 0, stream>>>(
        XN, WmgS + (size_t)l * 524288, WmgS + (size_t)l * 524288 + 262144,
        bmg + l * 2048, nullptr, Hb, 16);
    k_gemm_single<1024, 2, 1><<<(Mtot / 128) * 2, 256, 0, stream>>>(
        Hb, WmoS + (size_t)l * 262144, nullptr, bmo + l * 256, X);
  }
  k_head<<<Bn, 256, 0, stream>>>(X, nfw, WHP, BHP, OUT);
}

// Round 5
// 2605.269 us; speedup vs baseline: 1.2105x; 1.0166x over previous
//
#include <hip/hip_runtime.h>

#define DEV static __device__ __forceinline__

typedef float f32x4 __attribute__((ext_vector_type(4)));
typedef short s16x8 __attribute__((ext_vector_type(8)));
typedef __bf16 bf16x8 __attribute__((ext_vector_type(8)));

DEV unsigned short f2bf(float f) {
  union { float f; unsigned u; } v; v.f = f;
  unsigned r = v.u + 0x7FFFu + ((v.u >> 16) & 1u);
  return (unsigned short)(r >> 16);
}
DEV float bf2f(unsigned short h) {
  union { unsigned u; float f; } v; v.u = ((unsigned)h) << 16;
  return v.f;
}
DEV void g2l16(const void* g, void* l) {
  __builtin_amdgcn_global_load_lds((const __attribute__((address_space(1))) void*)g,
                                   (__attribute__((address_space(3))) void*)l, 16, 0, 0);
}
DEV f32x4 mfma16(bf16x8 a, bf16x8 b, f32x4 c) {
  return __builtin_amdgcn_mfma_f32_16x16x32_bf16(a, b, c, 0, 0, 0);
}
// XCD-aware chunked swizzle; grid must be divisible by 8 (all our GEMM grids are).
DEV int xcd_swz(int bid, int nwg) {
  return (bid & 7) * (nwg >> 3) + (bid >> 3);
}
// tanh-approx gelu (max |err| vs exact ~3e-4, downstream impact ~2e-5)
DEV float gelu_t(float g) {
  float y = 0.7978845608028654f * (g + 0.044715f * g * g * g);
  float th = 1.f - 2.f * __builtin_amdgcn_rcpf(1.f + __expf(2.f * y));
  return 0.5f * g * (1.f + th);
}

// ---------------------------------------------------------------------------
// Precompute: Householder Q per layer.  Register-resident: lane t holds
// column t of Q in 64 VGPRs; v broadcast via shfl; no LDS.
// ---------------------------------------------------------------------------
__global__ void k_house(const float* __restrict__ VS, float* __restrict__ Qg) {
  const int l = blockIdx.x, t = threadIdx.x;  // 64 threads, t = column j
  float Qc[64];
#pragma unroll
  for (int i = 0; i < 64; i++) Qc[i] = (i == t) ? 1.f : 0.f;
  for (int rr = 0; rr < 32; rr++) {
    float vt = VS[(size_t)l * 2048 + rr * 64 + t];
    float vn = vt * vt;
#pragma unroll
    for (int o = 1; o < 64; o <<= 1) vn += __shfl_xor(vn, o, 64);
    float vv[64];
#pragma unroll
    for (int i = 0; i < 64; i++) vv[i] = __shfl(vt, i, 64);
    float w0 = 0.f, w1 = 0.f, w2 = 0.f, w3 = 0.f;
#pragma unroll
    for (int i = 0; i < 64; i += 4) {
      w0 = fmaf(vv[i + 0], Qc[i + 0], w0);
      w1 = fmaf(vv[i + 1], Qc[i + 1], w1);
      w2 = fmaf(vv[i + 2], Qc[i + 2], w2);
      w3 = fmaf(vv[i + 3], Qc[i + 3], w3);
    }
    float c = (2.f / (vn + 1e-8f)) * ((w0 + w1) + (w2 + w3));
#pragma unroll
    for (int i = 0; i < 64; i++) Qc[i] = fmaf(-vv[i], c, Qc[i]);
  }
#pragma unroll
  for (int i = 0; i < 64; i++) Qg[(size_t)l * 4096 + i * 64 + t] = Qc[i];
}

// ---------------------------------------------------------------------------
// Precompute: RoPE cos/sin tables [64 tokens][64 dims]
// ---------------------------------------------------------------------------
__global__ void k_rope(float* __restrict__ C, float* __restrict__ Sn) {
  int idx = blockIdx.x * 256 + threadIdx.x;
  if (idx >= 4096) return;
  int s = idx >> 6, d = idx & 63;
  int dh = d & 31;
  float coord = (dh < 16) ? (float)(s >> 3) : (float)(s & 7);
  int fi = dh & 15;
  float invf = powf(10000.f, -(float)fi / 16.f);
  float ang = coord * invf;
  C[idx] = cosf(ang);
  Sn[idx] = sinf(ang);
}

// ---------------------------------------------------------------------------
// Precompute: fold per-head Q^T into Wq,Wk; convert w_qkv -> chunked [N][K] bf16
// chunk layout (K-dim matrix width K): elem(m,k) at ((m>>4)*(K>>3)+(k>>3))*128+(m&15)*8+(k&7)
// ---------------------------------------------------------------------------
__global__ __launch_bounds__(256) void k_fold_qkv(const float* __restrict__ W,
                                                  const float* __restrict__ Qg,
                                                  unsigned short* __restrict__ out) {
  __shared__ float qrows[16 * 64];
  __shared__ float tr[16 * 256];
  const int l = blockIdx.x / 48, ng = blockIdx.x % 48;
  const int n0 = ng * 16, t = threadIdx.x;
  const float* Wl = W + (size_t)l * 256 * 768;
  float res[16];
  if (n0 < 512) {
    int part = n0 >> 8, h = (n0 & 255) >> 6, j0 = n0 & 63;
    for (int i = t; i < 1024; i += 256) {
      int jj = i >> 6, dd = i & 63;
      qrows[i] = Qg[(size_t)l * 4096 + (j0 + jj) * 64 + dd];
    }
    __syncthreads();
    const float* wrow = Wl + (size_t)t * 768 + part * 256 + h * 64;
    float wreg[64];
    for (int d = 0; d < 64; d++) wreg[d] = wrow[d];
    for (int jj = 0; jj < 16; jj++) {
      float a = 0.f;
      for (int d = 0; d < 64; d++) a += wreg[d] * qrows[jj * 64 + d];
      res[jj] = a;
    }
  } else {
    for (int jj = 0; jj < 16; jj++) res[jj] = Wl[(size_t)t * 768 + n0 + jj];
    __syncthreads();
  }
  __syncthreads();
  for (int jj = 0; jj < 16; jj++) tr[jj * 256 + t] = res[jj];
  __syncthreads();
  size_t base = (size_t)l * 196608 + (size_t)(n0 >> 4) * 4096;
  int kb = t >> 3, jn0 = (t & 7) * 2;
  s16x8 w0, w1;
  for (int u = 0; u < 8; u++) w0[u] = (short)f2bf(tr[jn0 * 256 + kb * 8 + u]);
  for (int u = 0; u < 8; u++) w1[u] = (short)f2bf(tr[(jn0 + 1) * 256 + kb * 8 + u]);
  *(s16x8*)(out + base + (size_t)t * 16) = w0;
  *(s16x8*)(out + base + (size_t)t * 16 + 8) = w1;
}

// ---------------------------------------------------------------------------
// Precompute: W2 = [w_out | w_out@w_gate] -> chunked [512][256] bf16
// ---------------------------------------------------------------------------
__global__ __launch_bounds__(256) void k_fold_w2(const float* __restrict__ WO,
                                                 const float* __restrict__ WG,
                                                 unsigned short* __restrict__ out) {
  __shared__ float wgs[256 * 16];
  __shared__ float tr[16 * 256];
  const int l = blockIdx.x >> 5, ng = blockIdx.x & 31;
  const int n0 = ng * 16, t = threadIdx.x;
  const float* WOl = WO + (size_t)l * 65536;
  float res[16];
  if (n0 < 256) {
    for (int jj = 0; jj < 16; jj++) res[jj] = WOl[(size_t)t * 256 + n0 + jj];
  } else {
    int c0 = n0 - 256;
    const float* WGl = WG + (size_t)l * 65536;
    for (int i = t; i < 4096; i += 256) {
      int k = i >> 4, c = i & 15;
      wgs[i] = WGl[(size_t)k * 256 + c0 + c];
    }
    __syncthreads();
    float a[16];
    for (int c = 0; c < 16; c++) a[c] = 0.f;
    for (int k = 0; k < 256; k++) {
      float wo = WOl[(size_t)t * 256 + k];
      for (int c = 0; c < 16; c++) a[c] += wo * wgs[k * 16 + c];
    }
    for (int c = 0; c < 16; c++) res[c] = a[c];
  }
  __syncthreads();
  for (int jj = 0; jj < 16; jj++) tr[jj * 256 + t] = res[jj];
  __syncthreads();
  size_t base = (size_t)l * 131072 + (size_t)(n0 >> 4) * 4096;
  int kb = t >> 3, jn0 = (t & 7) * 2;
  s16x8 w0, w1;
  for (int u = 0; u < 8; u++) w0[u] = (short)f2bf(tr[jn0 * 256 + kb * 8 + u]);
  for (int u = 0; u < 8; u++) w1[u] = (short)f2bf(tr[(jn0 + 1) * 256 + kb * 8 + u]);
  *(s16x8*)(out + base + (size_t)t * 16) = w0;
  *(s16x8*)(out + base + (size_t)t * 16 + 8) = w1;
}

// ---------------------------------------------------------------------------
// Precompute: w_mlp_gate [256][2048] -> chunked [2048][256] bf16
// ---------------------------------------------------------------------------
__global__ __launch_bounds__(256) void k_conv_wmg(const float* __restrict__ W,
                                                  unsigned short* __restrict__ out) {
  __shared__ float tr[16 * 256];
  const int l = blockIdx.x >> 7, ng = blockIdx.x & 127;
  const int n0 = ng * 16, t = threadIdx.x;
  const float* src = W + (size_t)l * 256 * 2048 + (size_t)t * 2048 + n0;
  for (int j = 0; j < 16; j++) tr[j * 256 + t] = src[j];
  __syncthreads();
  size_t base = (size_t)l * 524288 + (size_t)ng * 4096;
  int kb = t >> 3, jn0 = (t & 7) * 2;
  s16x8 w0, w1;
  for (int u = 0; u < 8; u++) w0[u] = (short)f2bf(tr[jn0 * 256 + kb * 8 + u]);
  for (int u = 0; u < 8; u++) w1[u] = (short)f2bf(tr[(jn0 + 1) * 256 + kb * 8 + u]);
  *(s16x8*)(out + base + (size_t)t * 16) = w0;
  *(s16x8*)(out + base + (size_t)t * 16 + 8) = w1;
}

// ---------------------------------------------------------------------------
// Precompute: w_mlp_out [1024][256] -> chunked [256][1024] bf16
// ---------------------------------------------------------------------------
__global__ __launch_bounds__(256) void k_conv_wmo(const float* __restrict__ W,
                                                  unsigned short* __restrict__ out) {
  __shared__ float tr[16 * 256];
  const int l = blockIdx.x >> 4, ng = blockIdx.x & 15;
  const int n0 = ng * 16, t = threadIdx.x;
  const float* Wl = W + (size_t)l * 1024 * 256;
  size_t base = (size_t)l * 262144 + (size_t)ng * 16384;
  for (int c4 = 0; c4 < 4; c4++) {
    int k0 = c4 * 256;
    for (int j = 0; j < 16; j++) tr[j * 256 + t] = Wl[(size_t)(k0 + t) * 256 + n0 + j];
    __syncthreads();
    int kb = t >> 3, jn0 = (t & 7) * 2;
    s16x8 w0, w1;
    for (int u = 0; u < 8; u++) w0[u] = (short)f2bf(tr[jn0 * 256 + kb * 8 + u]);
    for (int u = 0; u < 8; u++) w1[u] = (short)f2bf(tr[(jn0 + 1) * 256 + kb * 8 + u]);
    *(s16x8*)(out + base + (size_t)(k0 >> 3) * 128 + (size_t)t * 16) = w0;
    *(s16x8*)(out + base + (size_t)(k0 >> 3) * 128 + (size_t)t * 16 + 8) = w1;
    __syncthreads();
  }
}

// ---------------------------------------------------------------------------
// Precompute: Whp = w_head @ w_patch_out [256][12], bhp = b_head@w_patch_out + b_patch_out
// ---------------------------------------------------------------------------
__global__ __launch_bounds__(256) void k_fold_head(const float* __restrict__ WH,
                                                   const float* __restrict__ BH,
                                                   const float* __restrict__ WPO,
                                                   const float* __restrict__ BPO,
                                                   float* __restrict__ WHP,
                                                   float* __restrict__ BHP) {
  __shared__ float wpos[256 * 12];
  const int t = threadIdx.x;
  for (int i = t; i < 3072; i += 256) wpos[i] = WPO[i];
  __syncthreads();
  float a[12];
  for (int c = 0; c < 12; c++) a[c] = 0.f;
  const float* whrow = WH + (size_t)t * 256;
  for (int k = 0; k < 256; k++) {
    float w = whrow[k];
    for (int c = 0; c < 12; c++) a[c] += w * wpos[k * 12 + c];
  }
  for (int c = 0; c < 12; c++) WHP[t * 12 + c] = a[c];
  if (t < 12) {
    float b = BPO[t];
    for (int k = 0; k < 256; k++) b += BH[k] * wpos[k * 12 + t];
    BHP[t] = b;
  }
}

// ---------------------------------------------------------------------------
// Embed: patchify + fourier features -> x [M,256] f32
// ---------------------------------------------------------------------------
__global__ __launch_bounds__(256) void k_embed(const float* __restrict__ ZT,
                                               const float* __restrict__ LOGSNR,
                                               const float* __restrict__ WPI,
                                               const float* __restrict__ BPI,
                                               float* __restrict__ X) {
  __shared__ float zb[768];
  __shared__ float sp[8];
  const int b = blockIdx.x, t = threadIdx.x;
  for (int i = t; i < 768; i += 256) zb[i] = ZT[(size_t)b * 768 + i];
  if (t < 8) {
    float freq = 0.15707963267948966f * (float)(1 << (t & 3));  // 2pi/40 * 2^k
    float a = LOGSNR[b] * freq;
    sp[t] = (t < 4) ? sinf(a) : cosf(a);
  }
  __syncthreads();
  float wc[20];
  for (int j = 0; j < 20; j++) wc[j] = WPI[j * 256 + t];
  float bk = BPI[t];
  for (int s = 0; s < 64; s++) {
    int gy = s >> 3, gx = s & 7;
    float acc = bk;
    for (int j = 0; j < 12; j++) {
      int cch = j >> 2, py = (j >> 1) & 1, px = j & 1;
      acc += zb[cch * 256 + (gy * 2 + py) * 16 + gx * 2 + px] * wc[j];
    }
    for (int j = 0; j < 8; j++) acc += sp[j] * wc[12 + j];
    X[((size_t)b * 64 + s) * 256 + t] = acc;
  }
}

// ---------------------------------------------------------------------------
// RMS norm: x f32 [M,256] -> xn chunked bf16.  One block = 16 rows.
// ---------------------------------------------------------------------------
__global__ __launch_bounds__(256) void k_rms(const float* __restrict__ X,
                                             unsigned short* __restrict__ XN) {
  const int m0 = blockIdx.x * 16, t = threadIdx.x;
  const int r = t >> 4, cj = t & 15;
  const float* row = X + (size_t)(m0 + r) * 256 + cj * 16;
  float4 a = *(const float4*)(row);
  float4 b = *(const float4*)(row + 4);
  float4 c = *(const float4*)(row + 8);
  float4 d = *(const float4*)(row + 12);
  float ss = a.x * a.x + a.y * a.y + a.z * a.z + a.w * a.w +
             b.x * b.x + b.y * b.y + b.z * b.z + b.w * b.w +
             c.x * c.x + c.y * c.y + c.z * c.z + c.w * c.w +
             d.x * d.x + d.y * d.y + d.z * d.z + d.w * d.w;
  for (int o = 1; o < 16; o <<= 1) ss += __shfl_xor(ss, o, 64);
  float rq = rsqrtf(ss * (1.f / 256.f) + 1.1920929e-07f);
  s16x8 v0, v1;
  v0[0] = (short)f2bf(a.x * rq); v0[1] = (short)f2bf(a.y * rq);
  v0[2] = (short)f2bf(a.z * rq); v0[3] = (short)f2bf(a.w * rq);
  v0[4] = (short)f2bf(b.x * rq); v0[5] = (short)f2bf(b.y * rq);
  v0[6] = (short)f2bf(b.z * rq); v0[7] = (short)f2bf(b.w * rq);
  v1[0] = (short)f2bf(c.x * rq); v1[1] = (short)f2bf(c.y * rq);
  v1[2] = (short)f2bf(c.z * rq); v1[3] = (short)f2bf(c.w * rq);
  v1[4] = (short)f2bf(d.x * rq); v1[5] = (short)f2bf(d.y * rq);
  v1[6] = (short)f2bf(d.z * rq); v1[7] = (short)f2bf(d.w * rq);
  size_t base = ((size_t)blockIdx.x * 32 + cj * 2) * 128 + r * 8;
  *(s16x8*)(XN + base) = v0;
  *(s16x8*)(XN + base + 128) = v1;
}

// ---------------------------------------------------------------------------
// GEMM single-B (128x128 tile, m97 structure).  MODE 0: store bf16 row-major
// (width NT*128).  MODE 1: X[r][c] += acc + bias[c].
// A and Bw are chunked-layout bf16.  Epilogue staging stride 136 (pad vs 128)
// kills the 4-way LDS write conflict; 272 B rows keep b128 reads aligned.
// ---------------------------------------------------------------------------
template <int KD, int NT, int MODE>
__global__ __launch_bounds__(256) void k_gemm_single(const unsigned short* __restrict__ A,
                                                     const unsigned short* __restrict__ Bw,
                                                     unsigned short* __restrict__ Cout,
                                                     const float* __restrict__ bias,
                                                     float* __restrict__ X) {
  __shared__ unsigned short sm[17408];
  unsigned short* la = sm;
  unsigned short* lb = sm + 4096;
  const int t = threadIdx.x;
  const int lane = t & 63, wv = t >> 6;
  const int swz = xcd_swz(blockIdx.x, gridDim.x);
  const int bm = swz / NT, bn = swz % NT;
  const int m0 = bm * 128, n0 = bn * 128;
  const int wm = wv >> 1, wn = wv & 1;
  constexpr int KB8 = KD >> 3;

  f32x4 acc[4][4];
  f32x4 zz = {0.f, 0.f, 0.f, 0.f};
  for (int i = 0; i < 4; i++)
    for (int j = 0; j < 4; j++) acc[i][j] = zz;

  for (int k0 = 0; k0 < KD; k0 += 32) {
    const int kb0 = k0 >> 3;
    for (int ii = 0; ii < 2; ii++) {
      size_t mg = (size_t)(m0 >> 4) + ii * 4 + wv;
      g2l16(A + (mg * KB8 + kb0) * 128 + lane * 8, la + (ii * 4 + wv) * 512 + lane * 8);
    }
    for (int ii = 0; ii < 2; ii++) {
      size_t ng = (size_t)(n0 >> 4) + ii * 4 + wv;
      g2l16(Bw + (ng * KB8 + kb0) * 128 + lane * 8, lb + (ii * 4 + wv) * 512 + lane * 8);
    }
    __syncthreads();
    bf16x8 af[4], bb[4];
    for (int i = 0; i < 4; i++) af[i] = *(const bf16x8*)(la + (wm * 4 + i) * 512 + lane * 8);
    for (int j = 0; j < 4; j++) bb[j] = *(const bf16x8*)(lb + (wn * 4 + j) * 512 + lane * 8);
    for (int i = 0; i < 4; i++)
      for (int j = 0; j < 4; j++) acc[i][j] = mfma16(af[i], bb[j], acc[i][j]);
    __syncthreads();
  }

  const int lr = lane & 15, lg = lane >> 4;
  if constexpr (MODE == 0) {
    unsigned short* lc = sm;
    for (int i = 0; i < 4; i++)
      for (int j = 0; j < 4; j++)
        for (int e = 0; e < 4; e++) {
          int r = wm * 64 + i * 16 + lg * 4 + e;
          int c = wn * 64 + j * 16 + lr;
          lc[r * 136 + c] = f2bf(acc[i][j][e]);
        }
    __syncthreads();
    for (int p = 0; p < 8; p++) {
      int r = p * 16 + (t >> 4);
      int c = (t & 15) * 8;
      *(s16x8*)(Cout + (size_t)(m0 + r) * (NT * 128) + n0 + c) = *(const s16x8*)(lc + r * 136 + c);
    }
  } else {
    for (int i = 0; i < 4; i++)
      for (int j = 0; j < 4; j++) {
        int c = n0 + wn * 64 + j * 16 + lr;
        float bv = bias[c];
        for (int e = 0; e < 4; e++) {
          int r = m0 + wm * 64 + i * 16 + lg * 4 + e;
          X[(size_t)r * 256 + c] += acc[i][j][e] + bv;
        }
      }
  }
}

// ---------------------------------------------------------------------------
// GEMM dual-B (128x64 tile per set).  MODE 0 (attn out+gate):
//   X += acc0 * sigmoid(acc1 + bias[c]).
// MODE 1 (mlp gate): h = (acc1+bias[1024+c]) * gelu(acc0+bias[c]) -> chunked bf16 Hout.
// Epilogue staging stride 72 (pad vs 64): 144 B rows, b128-aligned, 2-way max.
// ---------------------------------------------------------------------------
template <int KD, int MODE>
__global__ __launch_bounds__(256) void k_gemm_dual(const unsigned short* __restrict__ A,
                                                   const unsigned short* __restrict__ B0,
                                                   const unsigned short* __restrict__ B1,
                                                   const float* __restrict__ bias,
                                                   float* __restrict__ X,
                                                   unsigned short* __restrict__ Hout,
                                                   int NT) {
  __shared__ unsigned short sm[9216];
  unsigned short* la = sm;
  unsigned short* lb0 = sm + 4096;
  unsigned short* lb1 = sm + 6144;
  const int t = threadIdx.x, lane = t & 63, wv = t >> 6;
  const int swz = xcd_swz(blockIdx.x, gridDim.x);
  const int bm = swz / NT, bn = swz % NT;
  const int m0 = bm * 128, n0 = bn * 64;
  constexpr int KB8 = KD >> 3;
  f32x4 acc0[2][4], acc1[2][4];
  f32x4 zz = {0.f, 0.f, 0.f, 0.f};
  for (int i = 0; i < 2; i++)
    for (int j = 0; j < 4; j++) { acc0[i][j] = zz; acc1[i][j] = zz; }

  for (int k0 = 0; k0 < KD; k0 += 32) {
    const int kb0 = k0 >> 3;
    for (int ii = 0; ii < 2; ii++) {
      size_t mg = (size_t)(m0 >> 4) + ii * 4 + wv;
      g2l16(A + (mg * KB8 + kb0) * 128 + lane * 8, la + (ii * 4 + wv) * 512 + lane * 8);
    }
    size_t ng = (size_t)(n0 >> 4) + wv;
    g2l16(B0 + (ng * KB8 + kb0) * 128 + lane * 8, lb0 + wv * 512 + lane * 8);
    g2l16(B1 + (ng * KB8 + kb0) * 128 + lane * 8, lb1 + wv * 512 + lane * 8);
    __syncthreads();
    bf16x8 af[2];
    for (int i = 0; i < 2; i++) af[i] = *(const bf16x8*)(la + (wv * 2 + i) * 512 + lane * 8);
    for (int j = 0; j < 4; j++) {
      bf16x8 b0 = *(const bf16x8*)(lb0 + j * 512 + lane * 8);
      bf16x8 b1 = *(const bf16x8*)(lb1 + j * 512 + lane * 8);
      for (int i = 0; i < 2; i++) {
        acc0[i][j] = mfma16(af[i], b0, acc0[i][j]);
        acc1[i][j] = mfma16(af[i], b1, acc1[i][j]);
      }
    }
    __syncthreads();
  }

  const int lr = lane & 15, lg = lane >> 4;
  if constexpr (MODE == 0) {
    for (int i = 0; i < 2; i++)
      for (int j = 0; j < 4; j++) {
        int c = n0 + j * 16 + lr;
        float bv = bias[c];
        for (int e = 0; e < 4; e++) {
          int r = m0 + wv * 32 + i * 16 + lg * 4 + e;
          float o = acc0[i][j][e];
          float g = acc1[i][j][e] + bv;
          X[(size_t)r * 256 + c] += o * __builtin_amdgcn_rcpf(1.f + __expf(-g));
        }
      }
  } else {
    unsigned short* lc = sm;
    for (int i = 0; i < 2; i++)
      for (int j = 0; j < 4; j++) {
        int cl = j * 16 + lr;
        float bg_ = bias[n0 + cl];
        float bv_ = bias[1024 + n0 + cl];
        for (int e = 0; e < 4; e++) {
          int rl = wv * 32 + i * 16 + lg * 4 + e;
          float g = acc0[i][j][e] + bg_;
          float vv = acc1[i][j][e] + bv_;
          lc[rl * 72 + cl] = f2bf(vv * gelu_t(g));
        }
      }
    __syncthreads();
    for (int it = 0; it < 4; it++) {
      int idx = it * 2048 + t * 8;
      int mg_l = idx >> 10, rem = idx & 1023;
      int kb_l = rem >> 7, r = (rem >> 3) & 15;
      *(s16x8*)(Hout + ((size_t)((m0 >> 4) + mg_l) * 128 + (n0 >> 3) + kb_l) * 128 + r * 8) =
          *(const s16x8*)(lc + (mg_l * 16 + r) * 72 + kb_l * 8);
    }
  }
}

// ---------------------------------------------------------------------------
// Attention: one block per (b, h).  RoPE on load; scores via MFMA; masked
// softmax; P@V; writes AO in chunked layout (K=256 matrix).
// ---------------------------------------------------------------------------
__global__ __launch_bounds__(256) void k_attn(const unsigned short* __restrict__ QKV,
                                              const float* __restrict__ CT,
                                              const float* __restrict__ ST,
                                              unsigned short* __restrict__ AO,
                                              int use_local) {
  __shared__ unsigned short sm[16384];
  unsigned short* qs = sm;           // 4096 (reused for O staging)
  unsigned short* ks = sm + 4096;
  unsigned short* vt = sm + 8192;
  unsigned short* ps = sm + 12288;
  const int blk = blockIdx.x;
  const int b = blk >> 2, h = blk & 3;
  const int t = threadIdx.x, lane = t & 63, wv = t >> 6;
  const size_t rowbase = (size_t)b * 64 * 768;

  {
    int s = t >> 2, dq = (t & 3) * 8;
    const unsigned short* qrow = QKV + rowbase + (size_t)s * 768 + h * 64;
    s16x8 qlo = *(const s16x8*)(qrow + dq);
    s16x8 qhi = *(const s16x8*)(qrow + dq + 32);
    s16x8 klo = *(const s16x8*)(qrow + 256 + dq);
    s16x8 khi = *(const s16x8*)(qrow + 256 + dq + 32);
    s16x8 oql, oqh, okl, okh;
    for (int e = 0; e < 8; e++) {
      float cl = CT[s * 64 + dq + e], sl = ST[s * 64 + dq + e];
      float ch = CT[s * 64 + dq + 32 + e], sh = ST[s * 64 + dq + 32 + e];
      float ql = bf2f((unsigned short)qlo[e]), qh = bf2f((unsigned short)qhi[e]);
      oql[e] = (short)f2bf((ql * cl - qh * sl) * 0.125f);
      oqh[e] = (short)f2bf((qh * ch + ql * sh) * 0.125f);
      float kl = bf2f((unsigned short)klo[e]), kh = bf2f((unsigned short)khi[e]);
      okl[e] = (short)f2bf(kl * cl - kh * sl);
      okh[e] = (short)f2bf(kh * ch + kl * sh);
    }
    int off_lo = (((s >> 4) * 8 + (dq >> 3)) * 16 + (s & 15)) * 8;
    int off_hi = (((s >> 4) * 8 + (dq >> 3) + 4) * 16 + (s & 15)) * 8;
    *(s16x8*)(qs + off_lo) = oql;
    *(s16x8*)(qs + off_hi) = oqh;
    *(s16x8*)(ks + off_lo) = okl;
    *(s16x8*)(ks + off_hi) = okh;
    // V transposed into chunked layout [d][s]
    int d0 = (t & 3) * 16;
    s16x8 v0 = *(const s16x8*)(qrow + 512 + d0);
    s16x8 v1 = *(const s16x8*)(qrow + 512 + d0 + 8);
    for (int e = 0; e < 8; e++) {
      int d = d0 + e;
      vt[(((d >> 4) * 8 + (s >> 3)) * 16 + (d & 15)) * 8 + (s & 7)] = (unsigned short)v0[e];
      d = d0 + 8 + e;
      vt[(((d >> 4) * 8 + (s >> 3)) * 16 + (d & 15)) * 8 + (s & 7)] = (unsigned short)v1[e];
    }
  }
  __syncthreads();

  // scores: wave wv owns query rows wv*16..wv*16+15
  f32x4 sc[4];
  f32x4 zz = {0.f, 0.f, 0.f, 0.f};
  for (int j = 0; j < 4; j++) sc[j] = zz;
  for (int kk = 0; kk < 2; kk++) {
    bf16x8 aq = *(const bf16x8*)(qs + wv * 1024 + kk * 512 + lane * 8);
    for (int j = 0; j < 4; j++)
      sc[j] = mfma16(aq, *(const bf16x8*)(ks + j * 1024 + kk * 512 + lane * 8), sc[j]);
  }

  const int lr = lane & 15, lg = lane >> 4;
  for (int e = 0; e < 4; e++) {
    int sq = wv * 16 + lg * 4 + e;
    int yq = sq >> 3, xq = sq & 7;
    float mx = -1e30f;
    float vals[4];
    for (int j = 0; j < 4; j++) {
      int sk = j * 16 + lr;
      float v = sc[j][e];
      if (use_local) {
        int dy = yq - (sk >> 3), dx = xq - (sk & 7);
        if (dy * dy + dx * dx > 6) v = -1e30f;
      }
      vals[j] = v;
      mx = fmaxf(mx, v);
    }
    for (int o = 1; o < 16; o <<= 1) mx = fmaxf(mx, __shfl_xor(mx, o, 64));
    float sum = 0.f;
    for (int j = 0; j < 4; j++) {
      float p = __expf(vals[j] - mx);
      vals[j] = p;
      sum += p;
    }
    for (int o = 1; o < 16; o <<= 1) sum += __shfl_xor(sum, o, 64);
    float inv = __builtin_amdgcn_rcpf(sum);
    for (int j = 0; j < 4; j++) {
      int sk = j * 16 + lr;
      ps[((wv * 8 + (sk >> 3)) * 16 + (sq & 15)) * 8 + (sk & 7)] = f2bf(vals[j] * inv);
    }
  }
  __syncthreads();

  f32x4 oa[4];
  for (int j = 0; j < 4; j++) oa[j] = zz;
  for (int kk = 0; kk < 2; kk++) {
    bf16x8 ap = *(const bf16x8*)(ps + wv * 1024 + kk * 512 + lane * 8);
    for (int j = 0; j < 4; j++)
      oa[j] = mfma16(ap, *(const bf16x8*)(vt + j * 1024 + kk * 512 + lane * 8), oa[j]);
  }
  unsigned short* os = qs + wv * 1024;  // per-wave 16x64 staging
  for (int j = 0; j < 4; j++)
    for (int e = 0; e < 4; e++) os[(lg * 4 + e) * 64 + j * 16 + lr] = f2bf(oa[j][e]);
  __syncthreads();
  const size_t obase = ((size_t)(b * 4 + wv) * 32 + h * 8) * 128;
  for (int c = 0; c < 2; c++) {
    int idx = c * 64 + lane;
    int kb = idx >> 4, r = idx & 15;
    *(s16x8*)(AO + obase + (size_t)kb * 128 + r * 8) = *(const s16x8*)(os + r * 64 + kb * 8);
  }
}

// ---------------------------------------------------------------------------
// Final head: rms(x)*norm_w @ Whp + bhp -> unpatchify.  One block per b.
// ---------------------------------------------------------------------------
__global__ __launch_bounds__(256) void k_head(const float* __restrict__ X,
                                              const float* __restrict__ NW,
                                              const float* __restrict__ WHP,
                                              const float* __restrict__ BHP,
                                              float* __restrict__ OUT) {
  __shared__ float wh[256 * 12];
  __shared__ float nw[256];
  __shared__ float bh[12];
  const int b = blockIdx.x, t = threadIdx.x;
  for (int i = t; i < 3072; i += 256) wh[i] = WHP[i];
  nw[t] = NW[t];
  if (t < 12) bh[t] = BHP[t];
  __syncthreads();
  const int r = t >> 2, qd = t & 3;
  const float* row = X + ((size_t)b * 64 + r) * 256 + qd * 64;
  float ss = 0.f;
  for (int i = 0; i < 64; i++) ss += row[i] * row[i];
  ss += __shfl_xor(ss, 1, 64);
  ss += __shfl_xor(ss, 2, 64);
  float rq = rsqrtf(ss * (1.f / 256.f) + 1.1920929e-07f);
  float accs[12];
  for (int c = 0; c < 12; c++) accs[c] = 0.f;
  for (int i = 0; i < 64; i++) {
    float xf = row[i] * rq * nw[qd * 64 + i];
    const float* wr = wh + (qd * 64 + i) * 12;
    for (int c = 0; c < 12; c++) accs[c] += xf * wr[c];
  }
  for (int c = 0; c < 12; c++) {
    accs[c] += __shfl_xor(accs[c], 1, 64);
    accs[c] += __shfl_xor(accs[c], 2, 64);
  }
  int gy = r >> 3, gx = r & 7;
  for (int u = 0; u < 3; u++) {
    int c = qd * 3 + u;
    float val = accs[c] + bh[c];
    int ch = c >> 2, py = (c >> 1) & 1, px = c & 1;
    OUT[(size_t)b * 768 + ch * 256 + (gy * 2 + py) * 16 + (gx * 2 + px)] = val;
  }
}

// ---------------------------------------------------------------------------
extern "C" void kernel_launch(void* const* d_in, const int* in_sizes, int n_in,
                              void* d_out, int out_size, void* d_ws, size_t ws_size,
                              hipStream_t stream) {
  (void)n_in; (void)out_size; (void)ws_size;
  const float* z_t    = (const float*)d_in[0];
  const float* logsnr = (const float*)d_in[1];
  const float* wpi    = (const float*)d_in[2];
  const float* bpi    = (const float*)d_in[3];
  const float* vs     = (const float*)d_in[4];
  const float* wqkv   = (const float*)d_in[5];
  const float* wout   = (const float*)d_in[6];
  const float* wgate  = (const float*)d_in[7];
  const float* bgate  = (const float*)d_in[8];
  const float* wmg    = (const float*)d_in[9];
  const float* bmg    = (const float*)d_in[10];
  const float* wmo    = (const float*)d_in[11];
  const float* bmo    = (const float*)d_in[12];
  const float* nfw    = (const float*)d_in[13];
  const float* whead  = (const float*)d_in[14];
  const float* bhead  = (const float*)d_in[15];
  const float* wpo    = (const float*)d_in[16];
  const float* bpo    = (const float*)d_in[17];
  float* OUT = (float*)d_out;

  const int Bn = in_sizes[0] / 768;  // 1024
  const int Mtot = Bn * 64;          // 65536

  char* w = (char*)d_ws;
  auto alloc = [&](size_t bytes) {
    char* p = w;
    w += (bytes + 255) & ~(size_t)255;
    return p;
  };
  float* Qg  = (float*)alloc((size_t)8 * 4096 * 4);
  float* Ct  = (float*)alloc(4096 * 4);
  float* St  = (float*)alloc(4096 * 4);
  float* WHP = (float*)alloc(3072 * 4);
  float* BHP = (float*)alloc(64);
  unsigned short* WqkvS = (unsigned short*)alloc((size_t)8 * 768 * 256 * 2);
  unsigned short* W2S   = (unsigned short*)alloc((size_t)8 * 512 * 256 * 2);
  unsigned short* WmgS  = (unsigned short*)alloc((size_t)8 * 2048 * 256 * 2);
  unsigned short* WmoS  = (unsigned short*)alloc((size_t)8 * 256 * 1024 * 2);
  float* X = (float*)alloc((size_t)Mtot * 256 * 4);
  unsigned short* XN  = (unsigned short*)alloc((size_t)Mtot * 256 * 2);
  unsigned short* BIG = (unsigned short*)alloc((size_t)Mtot * 1024 * 2);
  unsigned short* QKVb = BIG;
  unsigned short* AOb  = BIG + (size_t)Mtot * 768;
  unsigned short* Hb   = BIG;

  k_house<<<8, 64, 0, stream>>>(vs, Qg);
  k_rope<<<16, 256, 0, stream>>>(Ct, St);
  k_fold_qkv<<<8 * 48, 256, 0, stream>>>(wqkv, Qg, WqkvS);
  k_fold_w2<<<8 * 32, 256, 0, stream>>>(wout, wgate, W2S);
  k_conv_wmg<<<8 * 128, 256, 0, stream>>>(wmg, WmgS);
  k_conv_wmo<<<8 * 16, 256, 0, stream>>>(wmo, WmoS);
  k_fold_head<<<1, 256, 0, stream>>>(whead, bhead, wpo, bpo, WHP, BHP);
  k_embed<<<Bn, 256, 0, stream>>>(z_t, logsnr, wpi, bpi, X);

  for (int l = 0; l < 8; l++) {
    k_rms<<<Mtot / 16, 256, 0, stream>>>(X, XN);
    k_gemm_single<256, 6, 0><<<(Mtot / 128) * 6, 256, 0, stream>>>(
        XN, WqkvS + (size_t)l * 196608, QKVb, nullptr, nullptr);
    k_attn<<<Bn * 4, 256, 0, stream>>>(QKVb, Ct, St, AOb, ((l + 1) % 4) ? 1 : 0);
    k_gemm_dual<256, 0><<<(Mtot / 128) * 4, 256, 0, stream>>>(
        AOb, W2S + (size_t)l * 131072, W2S + (size_t)l * 131072 + 65536,
        bgate + l * 256, X, nullptr, 4);
    k_rms<<<Mtot / 16, 256, 0, stream>>>(X, XN);
    k_gemm_dual<256, 1><<<(Mtot / 128) * 16, 256, 0, stream>>>(
        XN, WmgS + (size_t)l * 524288, WmgS + (size_t)l * 524288 + 262144,
        bmg + l * 2048, nullptr, Hb, 16);
    k_gemm_single<1024, 2, 1><<<(Mtot / 128) * 2, 256, 0, stream>>>(
        Hb, WmoS + (size_t)l * 262144, nullptr, bmo + l * 256, X);
  }
  k_head<<<Bn, 256, 0, stream>>>(X, nfw, WHP, BHP, OUT);
}